// Round 6
// baseline (1282.198 us; speedup 1.0000x reference)
//
#include <hip/hip_runtime.h>

static inline int ceil_div(int a, int b) { return (a + b - 1) / b; }

typedef __attribute__((ext_vector_type(8))) short short8;
typedef __attribute__((ext_vector_type(4))) float floatx4;

__device__ __forceinline__ unsigned short f2bf(float f) {
    unsigned int u = __float_as_uint(f);
    unsigned int r = (u + 0x7fffu + ((u >> 16) & 1u)) >> 16;
    return (unsigned short)r;
}
__device__ __forceinline__ float bf2f(unsigned short h) {
    return __uint_as_float(((unsigned int)h) << 16);
}

// ---------------- CSR build ----------------
__global__ __launch_bounds__(256) void count_deg_k(const int* __restrict__ edges,
                                                   int* __restrict__ deg, int E) {
    int e = blockIdx.x * blockDim.x + threadIdx.x;
    if (e < E) {
        atomicAdd(&deg[edges[2 * e]], 1);
        atomicAdd(&deg[edges[2 * e + 1]], 1);
    }
}

__global__ __launch_bounds__(1024) void scan1_k(const int* __restrict__ deg,
                                                int* __restrict__ excl,
                                                int* __restrict__ bsum, int Nv) {
    __shared__ int s[1024];
    int tid = threadIdx.x;
    int i = blockIdx.x * 1024 + tid;
    int v = (i < Nv) ? deg[i] : 0;
    s[tid] = v;
    __syncthreads();
    for (int off = 1; off < 1024; off <<= 1) {
        int t = (tid >= off) ? s[tid - off] : 0;
        __syncthreads();
        if (tid >= off) s[tid] += t;
        __syncthreads();
    }
    if (i < Nv) excl[i] = s[tid] - v;
    if (tid == 1023) bsum[blockIdx.x] = s[1023];
}

__global__ __launch_bounds__(64) void scan2_k(int* __restrict__ bsum, int nb) {
    __shared__ int s[64];
    int tid = threadIdx.x;
    int v = (tid < nb) ? bsum[tid] : 0;
    s[tid] = v;
    __syncthreads();
    for (int off = 1; off < 64; off <<= 1) {
        int t = (tid >= off) ? s[tid - off] : 0;
        __syncthreads();
        if (tid >= off) s[tid] += t;
        __syncthreads();
    }
    if (tid < nb) bsum[tid] = s[tid] - v;
}

__global__ __launch_bounds__(1024) void scan3_k(const int* __restrict__ excl,
                                                const int* __restrict__ bsum,
                                                const int* __restrict__ deg,
                                                int* __restrict__ rowptr,
                                                int* __restrict__ cursor, int Nv) {
    int i = blockIdx.x * 1024 + threadIdx.x;
    if (i < Nv) {
        int val = excl[i] + bsum[blockIdx.x];
        rowptr[i] = val;
        cursor[i] = val;
        if (i == Nv - 1) rowptr[Nv] = val + deg[i];
    }
}

__global__ __launch_bounds__(256) void fill_adj_k(const int* __restrict__ edges,
                                                  int* __restrict__ cursor,
                                                  int* __restrict__ adj, int E) {
    int e = blockIdx.x * blockDim.x + threadIdx.x;
    if (e < E) {
        int a = edges[2 * e], b = edges[2 * e + 1];
        adj[atomicAdd(&cursor[a], 1)] = b;
        adj[atomicAdd(&cursor[b], 1)] = a;
    }
}

// ---------------- weight prep: fp32 [K][128] -> bf16 transposed [128 n][128 k] ----------------
__global__ __launch_bounds__(256) void prep_w_k(const float* __restrict__ g0w0,
                                                const float* __restrict__ g0w1,
                                                const float* __restrict__ gw0,
                                                const float* __restrict__ gw1,
                                                unsigned short* __restrict__ Wt) {
    int lh = blockIdx.x;
    int l = lh >> 1, h = lh & 1;
    const float* src;
    if (l == 0) src = h ? g0w1 : g0w0;
    else src = (h ? gw1 : gw0) + (size_t)(l - 1) * 16384;
    unsigned short* dst = Wt + (size_t)lh * 16384;
    for (int idx = threadIdx.x; idx < 16384; idx += 256) {
        int n = idx >> 7, k = idx & 127;
        dst[n * 128 + k] = f2bf(src[k * 128 + n]);
    }
}

// ---------------- enc @ g0_w*[131:387] ----------------
__global__ __launch_bounds__(128) void enc_proj_k(const float* __restrict__ enc,
                                                  const float* __restrict__ w0,
                                                  const float* __restrict__ w1,
                                                  float* __restrict__ out, int B_) {
    int b = blockIdx.x, sH = blockIdx.y, j = threadIdx.x;
    const float* w = sH ? w1 : w0;
    const float* eb = enc + b * 256;
    float acc = 0.f;
    for (int c = 0; c < 256; ++c) acc = fmaf(eb[c], w[(131 + c) * 128 + j], acc);
    out[(sH * B_ + b) * 128 + j] = acc;
}

// ---------------- pixel projection, K-split -> disjoint partial buffers ----------------
__global__ __launch_bounds__(256) void gemm_proj_k(const float* __restrict__ fm,
                                                   const float* __restrict__ W,
                                                   float* __restrict__ out, int C, int HW,
                                                   int Cchunk, int S) {
    __shared__ float Xs[32][64];
    __shared__ float Ws[32][128];
    int tid = threadIdx.x;
    int p0 = blockIdx.x * 64;
    int b = blockIdx.y;
    int c0 = blockIdx.z * Cchunk;
    const float* fmb = fm + (size_t)b * C * HW;
    float acc[8][4];
#pragma unroll
    for (int i = 0; i < 8; i++)
#pragma unroll
        for (int j = 0; j < 4; j++) acc[i][j] = 0.f;

    bool vec_ok = ((HW & 3) == 0);
    for (int kc = c0; kc < c0 + Cchunk; kc += 32) {
        {
            int p4 = (tid & 15) * 4;
            int k0 = tid >> 4;
#pragma unroll
            for (int kk = 0; kk < 32; kk += 16) {
                int k = k0 + kk;
                const float* src = fmb + (size_t)(kc + k) * HW + p0 + p4;
                float4 v;
                if (vec_ok && (p0 + p4 + 3 < HW)) {
                    v = *(const float4*)src;
                } else {
                    v.x = (p0 + p4 + 0 < HW) ? src[0] : 0.f;
                    v.y = (p0 + p4 + 1 < HW) ? src[1] : 0.f;
                    v.z = (p0 + p4 + 2 < HW) ? src[2] : 0.f;
                    v.w = (p0 + p4 + 3 < HW) ? src[3] : 0.f;
                }
                *(float4*)&Xs[k][p4] = v;
            }
        }
        {
            int j4 = (tid & 31) * 4;
            int k0 = tid >> 5;
#pragma unroll
            for (int kk = 0; kk < 32; kk += 8) {
                int k = k0 + kk;
                *(float4*)&Ws[k][j4] = *(const float4*)(W + (size_t)(kc + k) * 128 + j4);
            }
        }
        __syncthreads();
        int rb = (tid >> 5) * 8;
        int cb = (tid & 31) * 4;
#pragma unroll 8
        for (int k = 0; k < 32; ++k) {
            float xr[8], wc[4];
#pragma unroll
            for (int i = 0; i < 8; i++) xr[i] = Xs[k][rb + i];
#pragma unroll
            for (int j = 0; j < 4; j++) wc[j] = Ws[k][cb + j];
#pragma unroll
            for (int i = 0; i < 8; i++)
#pragma unroll
                for (int j = 0; j < 4; j++) acc[i][j] = fmaf(xr[i], wc[j], acc[i][j]);
        }
        __syncthreads();
    }
    int rb = (tid >> 5) * 8;
    int cb = (tid & 31) * 4;
    float* obase = out + (size_t)blockIdx.z * S;
#pragma unroll
    for (int i = 0; i < 8; i++) {
        int p = p0 + rb + i;
        if (p < HW) {
            *(float4*)(obase + ((size_t)b * HW + p) * 128 + cb) =
                make_float4(acc[i][0], acc[i][1], acc[i][2], acc[i][3]);
        }
    }
}

// ---------------- reduce partials for levels 2/3/4 ----------------
__global__ __launch_bounds__(256) void reduce_pp_k(const float* __restrict__ p2,
                                                   const float* __restrict__ p3,
                                                   const float* __restrict__ p4,
                                                   float* __restrict__ o2,
                                                   float* __restrict__ o3,
                                                   float* __restrict__ o4, int S2, int S3,
                                                   int S4) {
    int idx4 = blockIdx.x * 256 + threadIdx.x;
    int i = idx4 * 4;
    const float* src;
    float* dst;
    int S, z, base;
    if (i < S2) {
        src = p2; dst = o2; S = S2; z = 4; base = i;
    } else if (i < S2 + S3) {
        src = p3; dst = o3; S = S3; z = 8; base = i - S2;
    } else if (i < S2 + S3 + S4) {
        src = p4; dst = o4; S = S4; z = 16; base = i - S2 - S3;
    } else {
        return;
    }
    float4 a = *(const float4*)(src + base);
    for (int zz = 1; zz < z; ++zz) {
        float4 b = *(const float4*)(src + (size_t)zz * S + base);
        a.x += b.x; a.y += b.y; a.z += b.z; a.w += b.w;
    }
    *(float4*)(dst + base) = a;
}

// ---------------- bilinear sample + bottleneck relu (bf16 X0) + layer0 pre terms (biases baked in) ----------------
__device__ __forceinline__ float sample_level(const float* __restrict__ pp, int Hh, int Ww,
                                              float gx, float gy, int j) {
    float x = (gx + 1.f) * 0.5f * (float)(Ww - 1);
    float y = (gy + 1.f) * 0.5f * (float)(Hh - 1);
    float x0f = floorf(x), y0f = floorf(y);
    float wx1 = x - x0f, wy1 = y - y0f;
    float wx0 = 1.f - wx1, wy0 = 1.f - wy1;
    int x0 = (int)fminf(fmaxf(x0f, 0.f), (float)(Ww - 1));
    int x1 = (int)fminf(fmaxf(x0f + 1.f, 0.f), (float)(Ww - 1));
    int y0 = (int)fminf(fmaxf(y0f, 0.f), (float)(Hh - 1));
    int y1 = (int)fminf(fmaxf(y0f + 1.f, 0.f), (float)(Hh - 1));
    const float* r00 = pp + (size_t)(y0 * Ww + x0) * 128;
    const float* r01 = pp + (size_t)(y0 * Ww + x1) * 128;
    const float* r10 = pp + (size_t)(y1 * Ww + x0) * 128;
    const float* r11 = pp + (size_t)(y1 * Ww + x1) * 128;
    return wy0 * (wx0 * r00[j] + wx1 * r01[j]) + wy1 * (wx0 * r10[j] + wx1 * r11[j]);
}

__global__ __launch_bounds__(128) void sample_bottleneck_k(
    const float* __restrict__ av, const float* __restrict__ pp1, const float* __restrict__ pp2,
    const float* __restrict__ pp3, const float* __restrict__ pp4, const float* __restrict__ bb,
    const float* __restrict__ verts, const float* __restrict__ encp,
    const float* __restrict__ g0w0, const float* __restrict__ g0w1,
    const float* __restrict__ g0b0, const float* __restrict__ g0b1,
    unsigned short* __restrict__ X, unsigned short* __restrict__ H, int V_, int B_) {
    int n = blockIdx.x, j = threadIdx.x;
    int b = n / V_;
    float gx = av[(size_t)n * 3 + 0];
    float gy = av[(size_t)n * 3 + 1];
    float acc = bb[j];
    acc += sample_level(pp1 + (size_t)b * 3136 * 128, 56, 56, gx, gy, j);
    acc += sample_level(pp2 + (size_t)b * 784 * 128, 28, 28, gx, gy, j);
    acc += sample_level(pp3 + (size_t)b * 196 * 128, 14, 14, gx, gy, j);
    acc += sample_level(pp4 + (size_t)b * 49 * 128, 7, 7, gx, gy, j);
    X[(size_t)n * 128 + j] = f2bf(fmaxf(acc, 0.f));
    float v0 = verts[n * 3 + 0], v1 = verts[n * 3 + 1], v2 = verts[n * 3 + 2];
    // h0pre includes b0; h1pre includes b1 -> aggregation auto-yields deg*b1
    float h0 = encp[(0 * B_ + b) * 128 + j] + g0b0[j] + v0 * g0w0[128 * 128 + j] +
               v1 * g0w0[129 * 128 + j] + v2 * g0w0[130 * 128 + j];
    float h1 = encp[(1 * B_ + b) * 128 + j] + g0b1[j] + v0 * g0w1[128 * 128 + j] +
               v1 * g0w1[129 * 128 + j] + v2 * g0w1[130 * 128 + j];
    H[(size_t)n * 256 + j] = f2bf(h0);
    H[(size_t)n * 256 + 128 + j] = f2bf(h1);
}

// ---------------- layer-0 pre: pre[n] = h0pre[n] + sum_nb h1pre[nb] (fp32) ----------------
__global__ __launch_bounds__(256) void aggpre_k(const unsigned short* __restrict__ H,
                                                const int* __restrict__ rowptr,
                                                const int* __restrict__ adj,
                                                float* __restrict__ pre, int Nv) {
    int wave = threadIdx.x >> 6, lane = threadIdx.x & 63;
    int n = blockIdx.x * 4 + wave;
    if (n >= Nv) return;
    unsigned int u = *(const unsigned int*)(H + (size_t)n * 256 + 2 * lane);
    float a0 = bf2f((unsigned short)(u & 0xffff));
    float a1 = bf2f((unsigned short)(u >> 16));
    int s = rowptr[n], e = rowptr[n + 1];
    for (int t = s; t < e; ++t) {
        int nb = adj[t];
        unsigned int w = *(const unsigned int*)(H + (size_t)nb * 256 + 128 + 2 * lane);
        a0 += bf2f((unsigned short)(w & 0xffff));
        a1 += bf2f((unsigned short)(w >> 16));
    }
    pre[(size_t)n * 128 + 2 * lane] = a0;
    pre[(size_t)n * 128 + 2 * lane + 1] = a1;
}

// ---------------- fused GraphConv layer ----------------
// x' = relu( X@W0 + (sum_nb X[nb])@W1 + b0 + deg*b1 + pre ).
// Block: 128 rows. Wave w aggregates + computes rows [w*32, w*32+32).
// AggX lives in LDS (XOR-swizzled 16B chunks); X and W fragments load from global.
// last: fused head out = relu'd-x' @ off_w + off_b instead of Xout.
__global__ __launch_bounds__(256, 2) void layer_fused_k(
    const unsigned short* __restrict__ Xin, const unsigned short* __restrict__ Wt,
    const float* __restrict__ b0, const float* __restrict__ b1,
    const float* __restrict__ pre, const int* __restrict__ rowptr,
    const int* __restrict__ adj, unsigned short* __restrict__ Xout,
    const float* __restrict__ off_w, const float* __restrict__ off_b,
    float* __restrict__ out, int last, int M) {
    __shared__ unsigned short CsS[128 * 136];  // gather phase uses pitch-128 region; epilogue pitch-136
    __shared__ int rps[129];
    __shared__ float bS[256];
    __shared__ float owS[384];
    __shared__ float phS[768];

    int tid = threadIdx.x;
    int m0 = blockIdx.x * 128;

    if (tid < 129) rps[tid] = rowptr[min(m0 + tid, M)];
    if (tid < 128) {
        bS[tid] = b0 ? b0[tid] : 0.f;
        bS[128 + tid] = b1 ? b1[tid] : 0.f;
    }
    if (last) {
        for (int i = tid; i < 384; i += 256) owS[i] = off_w[i];
    }
    __syncthreads();

    int wave = tid >> 6, lane = tid & 63;
    int row16 = lane & 15;
    int quad = lane >> 4;
    int wrow = wave * 32;
    const unsigned int* Xu = (const unsigned int*)Xin;

    // ---- gather phase: AggX rows for this wave ----
    for (int r = wrow; r < wrow + 32; ++r) {
        float a0 = 0.f, a1 = 0.f;
        if (m0 + r < M) {
            int s = rps[r], e = rps[r + 1];
            for (int t = s; t < e; ++t) {
                int nb = adj[t];
                unsigned int w = Xu[(size_t)nb * 64 + lane];
                a0 += bf2f((unsigned short)(w & 0xffff));
                a1 += bf2f((unsigned short)(w >> 16));
            }
        }
        unsigned int o = (unsigned int)f2bf(a0) | ((unsigned int)f2bf(a1) << 16);
        int chunk = lane >> 2;
        int idx = r * 128 + ((chunk ^ (r & 15)) * 8 + ((2 * lane) & 7));
        *(unsigned int*)&CsS[idx] = o;
    }

    // ---- MFMA phase (wave reads only its own Agg rows; compiler waits lgkm) ----
    floatx4 acc[2][8];
#pragma unroll
    for (int i = 0; i < 2; i++)
#pragma unroll
        for (int j = 0; j < 8; j++) acc[i][j] = (floatx4){0.f, 0.f, 0.f, 0.f};

#pragma unroll
    for (int ks = 0; ks < 4; ++ks) {
        int koff = ks * 32 + quad * 8;
        int r0 = min(m0 + wrow + row16, M - 1);
        int r1 = min(m0 + wrow + 16 + row16, M - 1);
        short8 ax0 = *(const short8*)(Xin + (size_t)r0 * 128 + koff);
        short8 ax1 = *(const short8*)(Xin + (size_t)r1 * 128 + koff);
        int c = ks * 4 + quad;
        short8 ag0 = *(short8*)&CsS[(wrow + row16) * 128 + ((c ^ row16) * 8)];
        short8 ag1 = *(short8*)&CsS[(wrow + 16 + row16) * 128 + ((c ^ row16) * 8)];
#pragma unroll
        for (int nt = 0; nt < 8; ++nt) {
            const unsigned short* wb = Wt + (nt * 16 + row16) * 128 + koff;
            short8 bw0 = *(const short8*)wb;
            short8 bw1 = *(const short8*)(wb + 16384);
            acc[0][nt] = __builtin_amdgcn_mfma_f32_16x16x32_bf16(ax0, bw0, acc[0][nt], 0, 0, 0);
            acc[0][nt] = __builtin_amdgcn_mfma_f32_16x16x32_bf16(ag0, bw1, acc[0][nt], 0, 0, 0);
            acc[1][nt] = __builtin_amdgcn_mfma_f32_16x16x32_bf16(ax1, bw0, acc[1][nt], 0, 0, 0);
            acc[1][nt] = __builtin_amdgcn_mfma_f32_16x16x32_bf16(ag1, bw1, acc[1][nt], 0, 0, 0);
        }
    }
    __syncthreads();  // Agg region done for all waves; now reuse as Cs (pitch 136)

    // ---- epilogue: bias + deg*b1 + pre, relu, -> Cs ----
#pragma unroll
    for (int rt = 0; rt < 2; ++rt) {
#pragma unroll
        for (int nt = 0; nt < 8; ++nt) {
            int col = nt * 16 + row16;
            float bc0 = bS[col];
            float bc1 = bS[128 + col];
#pragma unroll
            for (int rr = 0; rr < 4; ++rr) {
                int row = wrow + rt * 16 + quad * 4 + rr;
                float dg = (float)(rps[row + 1] - rps[row]);
                float v = acc[rt][nt][rr] + bc0 + dg * bc1;
                if (pre) {
                    int gm = min(m0 + row, M - 1);
                    v += pre[(size_t)gm * 128 + col];
                }
                CsS[row * 136 + col] = f2bf(fmaxf(v, 0.f));
            }
        }
    }
    __syncthreads();

    if (!last) {
        int r = tid >> 1;
        int ch = (tid & 1) * 64;
        int gm = m0 + r;
        if (gm < M) {
#pragma unroll
            for (int c = 0; c < 64; c += 8)
                *(short8*)(Xout + (size_t)gm * 128 + ch + c) = *(short8*)&CsS[r * 136 + ch + c];
        }
    } else {
        int r = tid >> 1;
        int half = tid & 1;
        float p0 = 0.f, p1 = 0.f, p2 = 0.f;
        int cbase = half * 64;
#pragma unroll 16
        for (int c = 0; c < 64; ++c) {
            float x = bf2f(CsS[r * 136 + cbase + c]);
            p0 = fmaf(x, owS[(cbase + c) * 3 + 0], p0);
            p1 = fmaf(x, owS[(cbase + c) * 3 + 1], p1);
            p2 = fmaf(x, owS[(cbase + c) * 3 + 2], p2);
        }
        phS[tid * 3 + 0] = p0;
        phS[tid * 3 + 1] = p1;
        phS[tid * 3 + 2] = p2;
        __syncthreads();
        if (tid < 128) {
            int gm = m0 + tid;
            if (gm < M) {
                out[gm * 3 + 0] = phS[(tid * 2) * 3 + 0] + phS[(tid * 2 + 1) * 3 + 0] + off_b[0];
                out[gm * 3 + 1] = phS[(tid * 2) * 3 + 1] + phS[(tid * 2 + 1) * 3 + 1] + off_b[1];
                out[gm * 3 + 2] = phS[(tid * 2) * 3 + 2] + phS[(tid * 2 + 1) * 3 + 2] + off_b[2];
            }
        }
    }
}

extern "C" void kernel_launch(void* const* d_in, const int* in_sizes, int n_in, void* d_out,
                              int out_size, void* d_ws, size_t ws_size, hipStream_t stream) {
    const float* feat1 = (const float*)d_in[0];
    const float* feat2 = (const float*)d_in[1];
    const float* feat3 = (const float*)d_in[2];
    const float* feat4 = (const float*)d_in[3];
    const float* av = (const float*)d_in[4];
    const float* verts = (const float*)d_in[5];
    const float* image_enc = (const float*)d_in[6];
    const int* edges = (const int*)d_in[7];
    const float* bw = (const float*)d_in[8];
    const float* bb = (const float*)d_in[9];
    const float* g0w0 = (const float*)d_in[10];
    const float* g0b0 = (const float*)d_in[11];
    const float* g0w1 = (const float*)d_in[12];
    const float* g0b1 = (const float*)d_in[13];
    const float* gw0 = (const float*)d_in[14];
    const float* gb0 = (const float*)d_in[15];
    const float* gw1 = (const float*)d_in[16];
    const float* gb1 = (const float*)d_in[17];
    const float* off_w = (const float*)d_in[18];
    const float* off_b = (const float*)d_in[19];

    int B_ = in_sizes[6] / 256;  // 4
    int N_ = in_sizes[5] / 3;    // 40968
    int V_ = N_ / B_;            // 10242
    int E_ = in_sizes[7] / 2;    // 122880

    char* wsb = (char*)d_ws;
    size_t off = 0;
    auto alloc = [&](size_t bytes) -> void* {
        void* p = (void*)(wsb + off);
        off += (bytes + 255) & ~(size_t)255;
        return p;
    };
    float* pp1 = (float*)alloc((size_t)B_ * 3136 * 128 * 4);
    float* pp2 = (float*)alloc((size_t)B_ * 784 * 128 * 4);
    float* pp3 = (float*)alloc((size_t)B_ * 196 * 128 * 4);
    float* pp4 = (float*)alloc((size_t)B_ * 49 * 128 * 4);
    unsigned short* XA = (unsigned short*)alloc((size_t)N_ * 128 * 2);
    unsigned short* XB = (unsigned short*)alloc((size_t)N_ * 128 * 2);
    unsigned short* Hb = (unsigned short*)alloc((size_t)N_ * 256 * 2);
    float* pre = (float*)alloc((size_t)N_ * 128 * 4);
    unsigned short* Wt = (unsigned short*)alloc((size_t)8 * 2 * 128 * 128 * 2);
    float* encp = (float*)alloc((size_t)2 * B_ * 128 * 4);
    int* deg = (int*)alloc((size_t)(N_ + 1) * 4);
    int* rowptr = (int*)alloc((size_t)(N_ + 1) * 4);
    int* cursor = (int*)alloc((size_t)N_ * 4);
    int* excl = (int*)alloc((size_t)N_ * 4);
    int* bsum = (int*)alloc((size_t)64 * 4);
    int* adj = (int*)alloc((size_t)2 * E_ * 4);

    // K-split partial buffers alias XA/XB (dead until sample_bottleneck_k)
    int S2 = B_ * 784 * 128;
    int S3 = B_ * 196 * 128;
    int S4 = B_ * 49 * 128;
    float* pp2p = (float*)XA;
    float* pp3p = (float*)XB;
    float* pp4p = (float*)((char*)XB + (size_t)8 * S3 * 4);

    // CSR build
    hipMemsetAsync(deg, 0, (N_ + 1) * sizeof(int), stream);
    count_deg_k<<<ceil_div(E_, 256), 256, 0, stream>>>(edges, deg, E_);
    int nb = ceil_div(N_, 1024);
    scan1_k<<<nb, 1024, 0, stream>>>(deg, excl, bsum, N_);
    scan2_k<<<1, 64, 0, stream>>>(bsum, nb);
    scan3_k<<<nb, 1024, 0, stream>>>(excl, bsum, deg, rowptr, cursor, N_);
    fill_adj_k<<<ceil_div(E_, 256), 256, 0, stream>>>(edges, cursor, adj, E_);

    // weight prep + enc projection
    prep_w_k<<<16, 256, 0, stream>>>(g0w0, g0w1, gw0, gw1, Wt);
    enc_proj_k<<<dim3(B_, 2), 128, 0, stream>>>(image_enc, g0w0, g0w1, encp, B_);

    // pixel projections: feat1 direct; feat2/3/4 K-split to partials + reduce
    gemm_proj_k<<<dim3(49, B_, 1), 256, 0, stream>>>(feat1, bw + 0 * 128, pp1, 256, 3136, 256, 0);
    gemm_proj_k<<<dim3(13, B_, 4), 256, 0, stream>>>(feat2, bw + 256 * 128, pp2p, 512, 784, 128, S2);
    gemm_proj_k<<<dim3(4, B_, 8), 256, 0, stream>>>(feat3, bw + 768 * 128, pp3p, 1024, 196, 128, S3);
    gemm_proj_k<<<dim3(1, B_, 16), 256, 0, stream>>>(feat4, bw + 1792 * 128, pp4p, 2048, 49, 128, S4);
    reduce_pp_k<<<ceil_div((S2 + S3 + S4) / 4, 256), 256, 0, stream>>>(pp2p, pp3p, pp4p, pp2,
                                                                       pp3, pp4, S2, S3, S4);

    // sample + bottleneck -> XA (bf16 X0); layer0 pre terms (biases baked) -> Hb (bf16)
    sample_bottleneck_k<<<N_, 128, 0, stream>>>(av, pp1, pp2, pp3, pp4, bb, verts, encp, g0w0,
                                                g0w1, g0b0, g0b1, XA, Hb, V_, B_);

    // layer0 pre = h0pre + sum_nb h1pre
    aggpre_k<<<ceil_div(N_, 4), 256, 0, stream>>>(Hb, rowptr, adj, pre, N_);

    int lgrid = ceil_div(N_, 128);
    // layer 0: pre supplies all affine terms
    layer_fused_k<<<lgrid, 256, 0, stream>>>(XA, Wt, nullptr, nullptr, pre, rowptr, adj, XB,
                                             off_w, off_b, (float*)d_out, 0, N_);
    unsigned short* Xc = XB;
    unsigned short* Xn = XA;
    for (int i = 0; i < 7; ++i) {
        int last = (i == 6) ? 1 : 0;
        layer_fused_k<<<lgrid, 256, 0, stream>>>(Xc, Wt + (size_t)(i + 1) * 32768, gb0 + i * 128,
                                                 gb1 + i * 128, nullptr, rowptr, adj, Xn, off_w,
                                                 off_b, (float*)d_out, last, N_);
        unsigned short* t = Xc;
        Xc = Xn;
        Xn = t;
    }
}

// Round 7
// 805.395 us; speedup vs baseline: 1.5920x; 1.5920x over previous
//
#include <hip/hip_runtime.h>

static inline int ceil_div(int a, int b) { return (a + b - 1) / b; }

typedef __attribute__((ext_vector_type(8))) short short8;
typedef __attribute__((ext_vector_type(4))) float floatx4;

__device__ __forceinline__ unsigned short f2bf(float f) {
    unsigned int u = __float_as_uint(f);
    unsigned int r = (u + 0x7fffu + ((u >> 16) & 1u)) >> 16;
    return (unsigned short)r;
}
__device__ __forceinline__ float bf2f(unsigned short h) {
    return __uint_as_float(((unsigned int)h) << 16);
}

// ---------------- CSR build ----------------
__global__ __launch_bounds__(256) void count_deg_k(const int* __restrict__ edges,
                                                   int* __restrict__ deg, int E) {
    int e = blockIdx.x * blockDim.x + threadIdx.x;
    if (e < E) {
        atomicAdd(&deg[edges[2 * e]], 1);
        atomicAdd(&deg[edges[2 * e + 1]], 1);
    }
}

__global__ __launch_bounds__(1024) void scan1_k(const int* __restrict__ deg,
                                                int* __restrict__ excl,
                                                int* __restrict__ bsum, int Nv) {
    __shared__ int s[1024];
    int tid = threadIdx.x;
    int i = blockIdx.x * 1024 + tid;
    int v = (i < Nv) ? deg[i] : 0;
    s[tid] = v;
    __syncthreads();
    for (int off = 1; off < 1024; off <<= 1) {
        int t = (tid >= off) ? s[tid - off] : 0;
        __syncthreads();
        if (tid >= off) s[tid] += t;
        __syncthreads();
    }
    if (i < Nv) excl[i] = s[tid] - v;
    if (tid == 1023) bsum[blockIdx.x] = s[1023];
}

__global__ __launch_bounds__(64) void scan2_k(int* __restrict__ bsum, int nb) {
    __shared__ int s[64];
    int tid = threadIdx.x;
    int v = (tid < nb) ? bsum[tid] : 0;
    s[tid] = v;
    __syncthreads();
    for (int off = 1; off < 64; off <<= 1) {
        int t = (tid >= off) ? s[tid - off] : 0;
        __syncthreads();
        if (tid >= off) s[tid] += t;
        __syncthreads();
    }
    if (tid < nb) bsum[tid] = s[tid] - v;
}

__global__ __launch_bounds__(1024) void scan3_k(const int* __restrict__ excl,
                                                const int* __restrict__ bsum,
                                                const int* __restrict__ deg,
                                                int* __restrict__ rowptr,
                                                int* __restrict__ cursor, int Nv) {
    int i = blockIdx.x * 1024 + threadIdx.x;
    if (i < Nv) {
        int val = excl[i] + bsum[blockIdx.x];
        rowptr[i] = val;
        cursor[i] = val;
        if (i == Nv - 1) rowptr[Nv] = val + deg[i];
    }
}

__global__ __launch_bounds__(256) void fill_adj_k(const int* __restrict__ edges,
                                                  int* __restrict__ cursor,
                                                  int* __restrict__ adj, int E) {
    int e = blockIdx.x * blockDim.x + threadIdx.x;
    if (e < E) {
        int a = edges[2 * e], b = edges[2 * e + 1];
        adj[atomicAdd(&cursor[a], 1)] = b;
        adj[atomicAdd(&cursor[b], 1)] = a;
    }
}

// ---------------- weight prep: fp32 [K][128] -> bf16 transposed [128 n][128 k] ----------------
__global__ __launch_bounds__(256) void prep_w_k(const float* __restrict__ g0w0,
                                                const float* __restrict__ g0w1,
                                                const float* __restrict__ gw0,
                                                const float* __restrict__ gw1,
                                                unsigned short* __restrict__ Wt) {
    int lh = blockIdx.x;
    int l = lh >> 1, h = lh & 1;
    const float* src;
    if (l == 0) src = h ? g0w1 : g0w0;
    else src = (h ? gw1 : gw0) + (size_t)(l - 1) * 16384;
    unsigned short* dst = Wt + (size_t)lh * 16384;
    for (int idx = threadIdx.x; idx < 16384; idx += 256) {
        int n = idx >> 7, k = idx & 127;
        dst[n * 128 + k] = f2bf(src[k * 128 + n]);
    }
}

// ---------------- enc @ g0_w*[131:387] ----------------
__global__ __launch_bounds__(128) void enc_proj_k(const float* __restrict__ enc,
                                                  const float* __restrict__ w0,
                                                  const float* __restrict__ w1,
                                                  float* __restrict__ out, int B_) {
    int b = blockIdx.x, sH = blockIdx.y, j = threadIdx.x;
    const float* w = sH ? w1 : w0;
    const float* eb = enc + b * 256;
    float acc = 0.f;
    for (int c = 0; c < 256; ++c) acc = fmaf(eb[c], w[(131 + c) * 128 + j], acc);
    out[(sH * B_ + b) * 128 + j] = acc;
}

// ---------------- pixel projection, K-split -> disjoint partial buffers ----------------
__global__ __launch_bounds__(256) void gemm_proj_k(const float* __restrict__ fm,
                                                   const float* __restrict__ W,
                                                   float* __restrict__ out, int C, int HW,
                                                   int Cchunk, int S) {
    __shared__ float Xs[32][64];
    __shared__ float Ws[32][128];
    int tid = threadIdx.x;
    int p0 = blockIdx.x * 64;
    int b = blockIdx.y;
    int c0 = blockIdx.z * Cchunk;
    const float* fmb = fm + (size_t)b * C * HW;
    float acc[8][4];
#pragma unroll
    for (int i = 0; i < 8; i++)
#pragma unroll
        for (int j = 0; j < 4; j++) acc[i][j] = 0.f;

    bool vec_ok = ((HW & 3) == 0);
    for (int kc = c0; kc < c0 + Cchunk; kc += 32) {
        {
            int p4 = (tid & 15) * 4;
            int k0 = tid >> 4;
#pragma unroll
            for (int kk = 0; kk < 32; kk += 16) {
                int k = k0 + kk;
                const float* src = fmb + (size_t)(kc + k) * HW + p0 + p4;
                float4 v;
                if (vec_ok && (p0 + p4 + 3 < HW)) {
                    v = *(const float4*)src;
                } else {
                    v.x = (p0 + p4 + 0 < HW) ? src[0] : 0.f;
                    v.y = (p0 + p4 + 1 < HW) ? src[1] : 0.f;
                    v.z = (p0 + p4 + 2 < HW) ? src[2] : 0.f;
                    v.w = (p0 + p4 + 3 < HW) ? src[3] : 0.f;
                }
                *(float4*)&Xs[k][p4] = v;
            }
        }
        {
            int j4 = (tid & 31) * 4;
            int k0 = tid >> 5;
#pragma unroll
            for (int kk = 0; kk < 32; kk += 8) {
                int k = k0 + kk;
                *(float4*)&Ws[k][j4] = *(const float4*)(W + (size_t)(kc + k) * 128 + j4);
            }
        }
        __syncthreads();
        int rb = (tid >> 5) * 8;
        int cb = (tid & 31) * 4;
#pragma unroll 8
        for (int k = 0; k < 32; ++k) {
            float xr[8], wc[4];
#pragma unroll
            for (int i = 0; i < 8; i++) xr[i] = Xs[k][rb + i];
#pragma unroll
            for (int j = 0; j < 4; j++) wc[j] = Ws[k][cb + j];
#pragma unroll
            for (int i = 0; i < 8; i++)
#pragma unroll
                for (int j = 0; j < 4; j++) acc[i][j] = fmaf(xr[i], wc[j], acc[i][j]);
        }
        __syncthreads();
    }
    int rb = (tid >> 5) * 8;
    int cb = (tid & 31) * 4;
    float* obase = out + (size_t)blockIdx.z * S;
#pragma unroll
    for (int i = 0; i < 8; i++) {
        int p = p0 + rb + i;
        if (p < HW) {
            *(float4*)(obase + ((size_t)b * HW + p) * 128 + cb) =
                make_float4(acc[i][0], acc[i][1], acc[i][2], acc[i][3]);
        }
    }
}

// ---------------- reduce partials for levels 2/3/4 ----------------
__global__ __launch_bounds__(256) void reduce_pp_k(const float* __restrict__ p2,
                                                   const float* __restrict__ p3,
                                                   const float* __restrict__ p4,
                                                   float* __restrict__ o2,
                                                   float* __restrict__ o3,
                                                   float* __restrict__ o4, int S2, int S3,
                                                   int S4) {
    int idx4 = blockIdx.x * 256 + threadIdx.x;
    int i = idx4 * 4;
    const float* src;
    float* dst;
    int S, z, base;
    if (i < S2) {
        src = p2; dst = o2; S = S2; z = 4; base = i;
    } else if (i < S2 + S3) {
        src = p3; dst = o3; S = S3; z = 8; base = i - S2;
    } else if (i < S2 + S3 + S4) {
        src = p4; dst = o4; S = S4; z = 16; base = i - S2 - S3;
    } else {
        return;
    }
    float4 a = *(const float4*)(src + base);
    for (int zz = 1; zz < z; ++zz) {
        float4 b = *(const float4*)(src + (size_t)zz * S + base);
        a.x += b.x; a.y += b.y; a.z += b.z; a.w += b.w;
    }
    *(float4*)(dst + base) = a;
}

// ---------------- bilinear sample + bottleneck relu + layer0 pre terms (biases baked in) ----------------
__device__ __forceinline__ float sample_level(const float* __restrict__ pp, int Hh, int Ww,
                                              float gx, float gy, int j) {
    float x = (gx + 1.f) * 0.5f * (float)(Ww - 1);
    float y = (gy + 1.f) * 0.5f * (float)(Hh - 1);
    float x0f = floorf(x), y0f = floorf(y);
    float wx1 = x - x0f, wy1 = y - y0f;
    float wx0 = 1.f - wx1, wy0 = 1.f - wy1;
    int x0 = (int)fminf(fmaxf(x0f, 0.f), (float)(Ww - 1));
    int x1 = (int)fminf(fmaxf(x0f + 1.f, 0.f), (float)(Ww - 1));
    int y0 = (int)fminf(fmaxf(y0f, 0.f), (float)(Hh - 1));
    int y1 = (int)fminf(fmaxf(y0f + 1.f, 0.f), (float)(Hh - 1));
    const float* r00 = pp + (size_t)(y0 * Ww + x0) * 128;
    const float* r01 = pp + (size_t)(y0 * Ww + x1) * 128;
    const float* r10 = pp + (size_t)(y1 * Ww + x0) * 128;
    const float* r11 = pp + (size_t)(y1 * Ww + x1) * 128;
    return wy0 * (wx0 * r00[j] + wx1 * r01[j]) + wy1 * (wx0 * r10[j] + wx1 * r11[j]);
}

__global__ __launch_bounds__(128) void sample_bottleneck_k(
    const float* __restrict__ av, const float* __restrict__ pp1, const float* __restrict__ pp2,
    const float* __restrict__ pp3, const float* __restrict__ pp4, const float* __restrict__ bb,
    const float* __restrict__ verts, const float* __restrict__ encp,
    const float* __restrict__ g0w0, const float* __restrict__ g0w1,
    const float* __restrict__ g0b0, const float* __restrict__ g0b1,
    unsigned short* __restrict__ X, unsigned short* __restrict__ H, int V_, int B_) {
    int n = blockIdx.x, j = threadIdx.x;
    int b = n / V_;
    float gx = av[(size_t)n * 3 + 0];
    float gy = av[(size_t)n * 3 + 1];
    float acc = bb[j];
    acc += sample_level(pp1 + (size_t)b * 3136 * 128, 56, 56, gx, gy, j);
    acc += sample_level(pp2 + (size_t)b * 784 * 128, 28, 28, gx, gy, j);
    acc += sample_level(pp3 + (size_t)b * 196 * 128, 14, 14, gx, gy, j);
    acc += sample_level(pp4 + (size_t)b * 49 * 128, 7, 7, gx, gy, j);
    X[(size_t)n * 128 + j] = f2bf(fmaxf(acc, 0.f));
    float v0 = verts[n * 3 + 0], v1 = verts[n * 3 + 1], v2 = verts[n * 3 + 2];
    float h0 = encp[(0 * B_ + b) * 128 + j] + g0b0[j] + v0 * g0w0[128 * 128 + j] +
               v1 * g0w0[129 * 128 + j] + v2 * g0w0[130 * 128 + j];
    float h1 = encp[(1 * B_ + b) * 128 + j] + g0b1[j] + v0 * g0w1[128 * 128 + j] +
               v1 * g0w1[129 * 128 + j] + v2 * g0w1[130 * 128 + j];
    H[(size_t)n * 256 + j] = f2bf(h0);
    H[(size_t)n * 256 + 128 + j] = f2bf(h1);
}

// ---------------- layer-0 pre: pre[n] = h0pre[n] + sum_nb h1pre[nb] (fp32) ----------------
__global__ __launch_bounds__(256) void aggpre_k(const unsigned short* __restrict__ H,
                                                const int* __restrict__ rowptr,
                                                const int* __restrict__ adj,
                                                float* __restrict__ pre, int Nv) {
    int wave = threadIdx.x >> 6, lane = threadIdx.x & 63;
    int n = blockIdx.x * 4 + wave;
    if (n >= Nv) return;
    unsigned int u = *(const unsigned int*)(H + (size_t)n * 256 + 2 * lane);
    float a0 = bf2f((unsigned short)(u & 0xffff));
    float a1 = bf2f((unsigned short)(u >> 16));
    int s = rowptr[n], e = rowptr[n + 1];
    for (int t = s; t < e; ++t) {
        int nb = adj[t];
        unsigned int w = *(const unsigned int*)(H + (size_t)nb * 256 + 128 + 2 * lane);
        a0 += bf2f((unsigned short)(w & 0xffff));
        a1 += bf2f((unsigned short)(w >> 16));
    }
    pre[(size_t)n * 128 + 2 * lane] = a0;
    pre[(size_t)n * 128 + 2 * lane + 1] = a1;
}

// ---------------- neighbor aggregation: Agg[n] = sum_nb X[nb] (bf16, fp32 acc) ----------------
// wave-per-vertex, N/4 blocks -> high TLP to hide gather latency.
__global__ __launch_bounds__(256) void agg_x_k(const unsigned short* __restrict__ X,
                                               const int* __restrict__ rowptr,
                                               const int* __restrict__ adj,
                                               unsigned short* __restrict__ Agg, int Nv) {
    int wave = threadIdx.x >> 6, lane = threadIdx.x & 63;
    int n = blockIdx.x * 4 + wave;
    if (n >= Nv) return;
    const unsigned int* Xu = (const unsigned int*)X;
    float a0 = 0.f, a1 = 0.f;
    int s = rowptr[n], e = rowptr[n + 1];
    for (int t = s; t < e; ++t) {
        int nb = adj[t];
        unsigned int w = Xu[(size_t)nb * 64 + lane];
        a0 += bf2f((unsigned short)(w & 0xffff));
        a1 += bf2f((unsigned short)(w >> 16));
    }
    unsigned int o = (unsigned int)f2bf(a0) | ((unsigned int)f2bf(a1) << 16);
    *(unsigned int*)(Agg + (size_t)n * 128 + 2 * lane) = o;
}

// ---------------- dual-MFMA layer GEMM: X' = relu(X@W0 + Agg@W1 + b0 + deg*b1 (+pre)) ----------------
// M-tile 64, 4 waves; wave w computes rows [w*16, w*16+16) x 128 cols.
// Weights read from global (64 KB working set, L2-resident).
__global__ __launch_bounds__(256, 4) void gemm_dual_k(
    const unsigned short* __restrict__ Xin, const unsigned short* __restrict__ Agg,
    const unsigned short* __restrict__ Wt,  // [2][128][128] bf16 n-major (W0, W1)
    const float* __restrict__ b0, const float* __restrict__ b1,
    const float* __restrict__ pre, const int* __restrict__ deg,
    unsigned short* __restrict__ Xout, const float* __restrict__ off_w,
    const float* __restrict__ off_b, float* __restrict__ out, int last, int M) {
    __shared__ unsigned short lds[16384];  // Xs [0,8192), As [8192,16384); epilogue Cs pitch-136
    unsigned short* Xs = lds;
    unsigned short* As = lds + 8192;
    __shared__ float bS[256];
    __shared__ float owS[384];
    __shared__ float phS[768];

    int tid = threadIdx.x;
    int m0 = blockIdx.x * 64;

    if (tid < 128) {
        bS[tid] = b0 ? b0[tid] : 0.f;
        bS[128 + tid] = b1 ? b1[tid] : 0.f;
    }
    if (last) {
        for (int i = tid; i < 384; i += 256) owS[i] = off_w[i];
    }

    // stage X and Agg tiles: 64 rows x 16 chunks(16B) = 1024 chunk slots, 4 per thread
#pragma unroll
    for (int l = 0; l < 4; ++l) {
        int idx = tid + l * 256;
        int r = idx >> 4;
        int c16 = idx & 15;
        int sw = (c16 ^ (r & 15)) * 8;
        short8 xv = {0, 0, 0, 0, 0, 0, 0, 0};
        short8 av = {0, 0, 0, 0, 0, 0, 0, 0};
        int gm = m0 + r;
        if (gm < M) {
            xv = *(const short8*)(Xin + (size_t)gm * 128 + c16 * 8);
            av = *(const short8*)(Agg + (size_t)gm * 128 + c16 * 8);
        }
        *(short8*)&Xs[r * 128 + sw] = xv;
        *(short8*)&As[r * 128 + sw] = av;
    }
    __syncthreads();

    int wave = tid >> 6, lane = tid & 63;
    int row16 = lane & 15;
    int quad = lane >> 4;
    int wrow = wave * 16;

    floatx4 acc[8];
#pragma unroll
    for (int j = 0; j < 8; j++) acc[j] = (floatx4){0.f, 0.f, 0.f, 0.f};

#pragma unroll
    for (int ks = 0; ks < 4; ++ks) {
        int c = ks * 4 + quad;
        int koff = ks * 32 + quad * 8;
        short8 ax = *(short8*)&Xs[(wrow + row16) * 128 + ((c ^ row16) * 8)];
        short8 ag = *(short8*)&As[(wrow + row16) * 128 + ((c ^ row16) * 8)];
#pragma unroll
        for (int nt = 0; nt < 8; ++nt) {
            const unsigned short* wb = Wt + (nt * 16 + row16) * 128 + koff;
            short8 bw0 = *(const short8*)wb;
            short8 bw1 = *(const short8*)(wb + 16384);
            acc[nt] = __builtin_amdgcn_mfma_f32_16x16x32_bf16(ax, bw0, acc[nt], 0, 0, 0);
            acc[nt] = __builtin_amdgcn_mfma_f32_16x16x32_bf16(ag, bw1, acc[nt], 0, 0, 0);
        }
    }
    __syncthreads();  // staging region done; reuse as Cs (64 x pitch-136 bf16 = 17408 B < 32768)

    unsigned short* Cs = lds;
#pragma unroll
    for (int nt = 0; nt < 8; ++nt) {
        int col = nt * 16 + row16;
        float bc0 = bS[col];
        float bc1 = bS[128 + col];
#pragma unroll
        for (int rr = 0; rr < 4; ++rr) {
            int row = wrow + quad * 4 + rr;
            int gm = m0 + row;
            float v = acc[nt][rr] + bc0;
            if (gm < M) {
                v += (float)deg[gm] * bc1;
                if (pre) v += pre[(size_t)gm * 128 + col];
            }
            Cs[row * 136 + col] = f2bf(fmaxf(v, 0.f));
        }
    }
    __syncthreads();

    if (!last) {
        int r = tid >> 2;
        int ch = (tid & 3) * 32;
        int gm = m0 + r;
        if (gm < M) {
#pragma unroll
            for (int c = 0; c < 32; c += 8)
                *(short8*)(Xout + (size_t)gm * 128 + ch + c) = *(short8*)&Cs[r * 136 + ch + c];
        }
    } else {
        int r = tid >> 2;
        int cbase = (tid & 3) * 32;
        float p0 = 0.f, p1 = 0.f, p2 = 0.f;
#pragma unroll 8
        for (int c = 0; c < 32; ++c) {
            float x = bf2f(Cs[r * 136 + cbase + c]);
            p0 = fmaf(x, owS[(cbase + c) * 3 + 0], p0);
            p1 = fmaf(x, owS[(cbase + c) * 3 + 1], p1);
            p2 = fmaf(x, owS[(cbase + c) * 3 + 2], p2);
        }
        phS[tid * 3 + 0] = p0;
        phS[tid * 3 + 1] = p1;
        phS[tid * 3 + 2] = p2;
        __syncthreads();
        if (tid < 64) {
            int gm = m0 + tid;
            if (gm < M) {
#pragma unroll
                for (int c = 0; c < 3; ++c) {
                    float s = phS[(tid * 4 + 0) * 3 + c] + phS[(tid * 4 + 1) * 3 + c] +
                              phS[(tid * 4 + 2) * 3 + c] + phS[(tid * 4 + 3) * 3 + c];
                    out[gm * 3 + c] = s + off_b[c];
                }
            }
        }
    }
}

extern "C" void kernel_launch(void* const* d_in, const int* in_sizes, int n_in, void* d_out,
                              int out_size, void* d_ws, size_t ws_size, hipStream_t stream) {
    const float* feat1 = (const float*)d_in[0];
    const float* feat2 = (const float*)d_in[1];
    const float* feat3 = (const float*)d_in[2];
    const float* feat4 = (const float*)d_in[3];
    const float* av = (const float*)d_in[4];
    const float* verts = (const float*)d_in[5];
    const float* image_enc = (const float*)d_in[6];
    const int* edges = (const int*)d_in[7];
    const float* bw = (const float*)d_in[8];
    const float* bb = (const float*)d_in[9];
    const float* g0w0 = (const float*)d_in[10];
    const float* g0b0 = (const float*)d_in[11];
    const float* g0w1 = (const float*)d_in[12];
    const float* g0b1 = (const float*)d_in[13];
    const float* gw0 = (const float*)d_in[14];
    const float* gb0 = (const float*)d_in[15];
    const float* gw1 = (const float*)d_in[16];
    const float* gb1 = (const float*)d_in[17];
    const float* off_w = (const float*)d_in[18];
    const float* off_b = (const float*)d_in[19];

    int B_ = in_sizes[6] / 256;  // 4
    int N_ = in_sizes[5] / 3;    // 40968
    int V_ = N_ / B_;            // 10242
    int E_ = in_sizes[7] / 2;    // 122880

    char* wsb = (char*)d_ws;
    size_t off = 0;
    auto alloc = [&](size_t bytes) -> void* {
        void* p = (void*)(wsb + off);
        off += (bytes + 255) & ~(size_t)255;
        return p;
    };
    float* pp1 = (float*)alloc((size_t)B_ * 3136 * 128 * 4);
    float* pp2 = (float*)alloc((size_t)B_ * 784 * 128 * 4);
    float* pp3 = (float*)alloc((size_t)B_ * 196 * 128 * 4);
    float* pp4 = (float*)alloc((size_t)B_ * 49 * 128 * 4);
    unsigned short* XA = (unsigned short*)alloc((size_t)N_ * 128 * 2);
    unsigned short* XB = (unsigned short*)alloc((size_t)N_ * 128 * 2);
    unsigned short* AggB = (unsigned short*)alloc((size_t)N_ * 128 * 2);
    unsigned short* Hb = (unsigned short*)alloc((size_t)N_ * 256 * 2);
    float* pre = (float*)alloc((size_t)N_ * 128 * 4);
    unsigned short* Wt = (unsigned short*)alloc((size_t)8 * 2 * 128 * 128 * 2);
    float* encp = (float*)alloc((size_t)2 * B_ * 128 * 4);
    int* deg = (int*)alloc((size_t)(N_ + 1) * 4);
    int* rowptr = (int*)alloc((size_t)(N_ + 1) * 4);
    int* cursor = (int*)alloc((size_t)N_ * 4);
    int* excl = (int*)alloc((size_t)N_ * 4);
    int* bsum = (int*)alloc((size_t)64 * 4);
    int* adj = (int*)alloc((size_t)2 * E_ * 4);

    // K-split partial buffers alias XA/XB (dead until sample_bottleneck_k)
    int S2 = B_ * 784 * 128;
    int S3 = B_ * 196 * 128;
    int S4 = B_ * 49 * 128;
    float* pp2p = (float*)XA;
    float* pp3p = (float*)XB;
    float* pp4p = (float*)((char*)XB + (size_t)8 * S3 * 4);

    // CSR build
    hipMemsetAsync(deg, 0, (N_ + 1) * sizeof(int), stream);
    count_deg_k<<<ceil_div(E_, 256), 256, 0, stream>>>(edges, deg, E_);
    int nb = ceil_div(N_, 1024);
    scan1_k<<<nb, 1024, 0, stream>>>(deg, excl, bsum, N_);
    scan2_k<<<1, 64, 0, stream>>>(bsum, nb);
    scan3_k<<<nb, 1024, 0, stream>>>(excl, bsum, deg, rowptr, cursor, N_);
    fill_adj_k<<<ceil_div(E_, 256), 256, 0, stream>>>(edges, cursor, adj, E_);

    // weight prep + enc projection
    prep_w_k<<<16, 256, 0, stream>>>(g0w0, g0w1, gw0, gw1, Wt);
    enc_proj_k<<<dim3(B_, 2), 128, 0, stream>>>(image_enc, g0w0, g0w1, encp, B_);

    // pixel projections: feat1 direct; feat2/3/4 K-split to partials + reduce
    gemm_proj_k<<<dim3(49, B_, 1), 256, 0, stream>>>(feat1, bw + 0 * 128, pp1, 256, 3136, 256, 0);
    gemm_proj_k<<<dim3(13, B_, 4), 256, 0, stream>>>(feat2, bw + 256 * 128, pp2p, 512, 784, 128, S2);
    gemm_proj_k<<<dim3(4, B_, 8), 256, 0, stream>>>(feat3, bw + 768 * 128, pp3p, 1024, 196, 128, S3);
    gemm_proj_k<<<dim3(1, B_, 16), 256, 0, stream>>>(feat4, bw + 1792 * 128, pp4p, 2048, 49, 128, S4);
    reduce_pp_k<<<ceil_div((S2 + S3 + S4) / 4, 256), 256, 0, stream>>>(pp2p, pp3p, pp4p, pp2,
                                                                       pp3, pp4, S2, S3, S4);

    // sample + bottleneck -> XA (bf16 X0); layer0 pre terms (biases baked) -> Hb (bf16)
    sample_bottleneck_k<<<N_, 128, 0, stream>>>(av, pp1, pp2, pp3, pp4, bb, verts, encp, g0w0,
                                                g0w1, g0b0, g0b1, XA, Hb, V_, B_);

    // layer0 pre = h0pre + sum_nb h1pre
    aggpre_k<<<ceil_div(N_, 4), 256, 0, stream>>>(Hb, rowptr, adj, pre, N_);

    int agrid = ceil_div(N_, 4);
    int ggrid = ceil_div(N_, 64);
    // layer 0: pre supplies all affine terms
    agg_x_k<<<agrid, 256, 0, stream>>>(XA, rowptr, adj, AggB, N_);
    gemm_dual_k<<<ggrid, 256, 0, stream>>>(XA, AggB, Wt, nullptr, nullptr, pre, deg, XB, off_w,
                                           off_b, (float*)d_out, 0, N_);
    unsigned short* Xc = XB;
    unsigned short* Xn = XA;
    for (int i = 0; i < 7; ++i) {
        int last = (i == 6) ? 1 : 0;
        agg_x_k<<<agrid, 256, 0, stream>>>(Xc, rowptr, adj, AggB, N_);
        gemm_dual_k<<<ggrid, 256, 0, stream>>>(Xc, AggB, Wt + (size_t)(i + 1) * 32768,
                                               gb0 + i * 128, gb1 + i * 128, nullptr, deg, Xn,
                                               off_w, off_b, (float*)d_out, last, N_);
        unsigned short* t = Xc;
        Xc = Xn;
        Xn = t;
    }
}

// Round 8
// 703.430 us; speedup vs baseline: 1.8228x; 1.1450x over previous
//
#include <hip/hip_runtime.h>

static inline int ceil_div(int a, int b) { return (a + b - 1) / b; }

typedef __attribute__((ext_vector_type(8))) short short8;
typedef __attribute__((ext_vector_type(4))) float floatx4;

__device__ __forceinline__ unsigned short f2bf(float f) {
    unsigned int u = __float_as_uint(f);
    unsigned int r = (u + 0x7fffu + ((u >> 16) & 1u)) >> 16;
    return (unsigned short)r;
}
__device__ __forceinline__ float bf2f(unsigned short h) {
    return __uint_as_float(((unsigned int)h) << 16);
}

// ---------------- CSR build ----------------
__global__ __launch_bounds__(256) void count_deg_k(const int* __restrict__ edges,
                                                   int* __restrict__ deg, int E) {
    int e = blockIdx.x * blockDim.x + threadIdx.x;
    if (e < E) {
        atomicAdd(&deg[edges[2 * e]], 1);
        atomicAdd(&deg[edges[2 * e + 1]], 1);
    }
}

__global__ __launch_bounds__(1024) void scan1_k(const int* __restrict__ deg,
                                                int* __restrict__ excl,
                                                int* __restrict__ bsum, int Nv) {
    __shared__ int s[1024];
    int tid = threadIdx.x;
    int i = blockIdx.x * 1024 + tid;
    int v = (i < Nv) ? deg[i] : 0;
    s[tid] = v;
    __syncthreads();
    for (int off = 1; off < 1024; off <<= 1) {
        int t = (tid >= off) ? s[tid - off] : 0;
        __syncthreads();
        if (tid >= off) s[tid] += t;
        __syncthreads();
    }
    if (i < Nv) excl[i] = s[tid] - v;
    if (tid == 1023) bsum[blockIdx.x] = s[1023];
}

__global__ __launch_bounds__(64) void scan2_k(int* __restrict__ bsum, int nb) {
    __shared__ int s[64];
    int tid = threadIdx.x;
    int v = (tid < nb) ? bsum[tid] : 0;
    s[tid] = v;
    __syncthreads();
    for (int off = 1; off < 64; off <<= 1) {
        int t = (tid >= off) ? s[tid - off] : 0;
        __syncthreads();
        if (tid >= off) s[tid] += t;
        __syncthreads();
    }
    if (tid < nb) bsum[tid] = s[tid] - v;
}

__global__ __launch_bounds__(1024) void scan3_k(const int* __restrict__ excl,
                                                const int* __restrict__ bsum,
                                                const int* __restrict__ deg,
                                                int* __restrict__ rowptr,
                                                int* __restrict__ cursor, int Nv) {
    int i = blockIdx.x * 1024 + threadIdx.x;
    if (i < Nv) {
        int val = excl[i] + bsum[blockIdx.x];
        rowptr[i] = val;
        cursor[i] = val;
        if (i == Nv - 1) rowptr[Nv] = val + deg[i];
    }
}

__global__ __launch_bounds__(256) void fill_adj_k(const int* __restrict__ edges,
                                                  int* __restrict__ cursor,
                                                  int* __restrict__ adj, int E) {
    int e = blockIdx.x * blockDim.x + threadIdx.x;
    if (e < E) {
        int a = edges[2 * e], b = edges[2 * e + 1];
        adj[atomicAdd(&cursor[a], 1)] = b;
        adj[atomicAdd(&cursor[b], 1)] = a;
    }
}

// ---------------- weight prep: fp32 [K][128] -> bf16 transposed [128 n][128 k] ----------------
__global__ __launch_bounds__(256) void prep_w_k(const float* __restrict__ g0w0,
                                                const float* __restrict__ g0w1,
                                                const float* __restrict__ gw0,
                                                const float* __restrict__ gw1,
                                                unsigned short* __restrict__ Wt) {
    int lh = blockIdx.x;
    int l = lh >> 1, h = lh & 1;
    const float* src;
    if (l == 0) src = h ? g0w1 : g0w0;
    else src = (h ? gw1 : gw0) + (size_t)(l - 1) * 16384;
    unsigned short* dst = Wt + (size_t)lh * 16384;
    for (int idx = threadIdx.x; idx < 16384; idx += 256) {
        int n = idx >> 7, k = idx & 127;
        dst[n * 128 + k] = f2bf(src[k * 128 + n]);
    }
}

// ---------------- enc @ g0_w*[131:387] ----------------
__global__ __launch_bounds__(128) void enc_proj_k(const float* __restrict__ enc,
                                                  const float* __restrict__ w0,
                                                  const float* __restrict__ w1,
                                                  float* __restrict__ out, int B_) {
    int b = blockIdx.x, sH = blockIdx.y, j = threadIdx.x;
    const float* w = sH ? w1 : w0;
    const float* eb = enc + b * 256;
    float acc = 0.f;
    for (int c = 0; c < 256; ++c) acc = fmaf(eb[c], w[(131 + c) * 128 + j], acc);
    out[(sH * B_ + b) * 128 + j] = acc;
}

// ---------------- pixel projection, K-split -> disjoint partial buffers ----------------
__global__ __launch_bounds__(256) void gemm_proj_k(const float* __restrict__ fm,
                                                   const float* __restrict__ W,
                                                   float* __restrict__ out, int C, int HW,
                                                   int Cchunk, int S) {
    __shared__ float Xs[32][64];
    __shared__ float Ws[32][128];
    int tid = threadIdx.x;
    int p0 = blockIdx.x * 64;
    int b = blockIdx.y;
    int c0 = blockIdx.z * Cchunk;
    const float* fmb = fm + (size_t)b * C * HW;
    float acc[8][4];
#pragma unroll
    for (int i = 0; i < 8; i++)
#pragma unroll
        for (int j = 0; j < 4; j++) acc[i][j] = 0.f;

    bool vec_ok = ((HW & 3) == 0);
    for (int kc = c0; kc < c0 + Cchunk; kc += 32) {
        {
            int p4 = (tid & 15) * 4;
            int k0 = tid >> 4;
#pragma unroll
            for (int kk = 0; kk < 32; kk += 16) {
                int k = k0 + kk;
                const float* src = fmb + (size_t)(kc + k) * HW + p0 + p4;
                float4 v;
                if (vec_ok && (p0 + p4 + 3 < HW)) {
                    v = *(const float4*)src;
                } else {
                    v.x = (p0 + p4 + 0 < HW) ? src[0] : 0.f;
                    v.y = (p0 + p4 + 1 < HW) ? src[1] : 0.f;
                    v.z = (p0 + p4 + 2 < HW) ? src[2] : 0.f;
                    v.w = (p0 + p4 + 3 < HW) ? src[3] : 0.f;
                }
                *(float4*)&Xs[k][p4] = v;
            }
        }
        {
            int j4 = (tid & 31) * 4;
            int k0 = tid >> 5;
#pragma unroll
            for (int kk = 0; kk < 32; kk += 8) {
                int k = k0 + kk;
                *(float4*)&Ws[k][j4] = *(const float4*)(W + (size_t)(kc + k) * 128 + j4);
            }
        }
        __syncthreads();
        int rb = (tid >> 5) * 8;
        int cb = (tid & 31) * 4;
#pragma unroll 8
        for (int k = 0; k < 32; ++k) {
            float xr[8], wc[4];
#pragma unroll
            for (int i = 0; i < 8; i++) xr[i] = Xs[k][rb + i];
#pragma unroll
            for (int j = 0; j < 4; j++) wc[j] = Ws[k][cb + j];
#pragma unroll
            for (int i = 0; i < 8; i++)
#pragma unroll
                for (int j = 0; j < 4; j++) acc[i][j] = fmaf(xr[i], wc[j], acc[i][j]);
        }
        __syncthreads();
    }
    int rb = (tid >> 5) * 8;
    int cb = (tid & 31) * 4;
    float* obase = out + (size_t)blockIdx.z * S;
#pragma unroll
    for (int i = 0; i < 8; i++) {
        int p = p0 + rb + i;
        if (p < HW) {
            *(float4*)(obase + ((size_t)b * HW + p) * 128 + cb) =
                make_float4(acc[i][0], acc[i][1], acc[i][2], acc[i][3]);
        }
    }
}

// ---------------- reduce partials for levels 2/3/4 ----------------
__global__ __launch_bounds__(256) void reduce_pp_k(const float* __restrict__ p2,
                                                   const float* __restrict__ p3,
                                                   const float* __restrict__ p4,
                                                   float* __restrict__ o2,
                                                   float* __restrict__ o3,
                                                   float* __restrict__ o4, int S2, int S3,
                                                   int S4) {
    int idx4 = blockIdx.x * 256 + threadIdx.x;
    int i = idx4 * 4;
    const float* src;
    float* dst;
    int S, z, base;
    if (i < S2) {
        src = p2; dst = o2; S = S2; z = 4; base = i;
    } else if (i < S2 + S3) {
        src = p3; dst = o3; S = S3; z = 8; base = i - S2;
    } else if (i < S2 + S3 + S4) {
        src = p4; dst = o4; S = S4; z = 16; base = i - S2 - S3;
    } else {
        return;
    }
    float4 a = *(const float4*)(src + base);
    for (int zz = 1; zz < z; ++zz) {
        float4 b = *(const float4*)(src + (size_t)zz * S + base);
        a.x += b.x; a.y += b.y; a.z += b.z; a.w += b.w;
    }
    *(float4*)(dst + base) = a;
}

// ---------------- bilinear sample + bottleneck relu + layer0 pre terms (biases baked in) ----------------
__device__ __forceinline__ float sample_level(const float* __restrict__ pp, int Hh, int Ww,
                                              float gx, float gy, int j) {
    float x = (gx + 1.f) * 0.5f * (float)(Ww - 1);
    float y = (gy + 1.f) * 0.5f * (float)(Hh - 1);
    float x0f = floorf(x), y0f = floorf(y);
    float wx1 = x - x0f, wy1 = y - y0f;
    float wx0 = 1.f - wx1, wy0 = 1.f - wy1;
    int x0 = (int)fminf(fmaxf(x0f, 0.f), (float)(Ww - 1));
    int x1 = (int)fminf(fmaxf(x0f + 1.f, 0.f), (float)(Ww - 1));
    int y0 = (int)fminf(fmaxf(y0f, 0.f), (float)(Hh - 1));
    int y1 = (int)fminf(fmaxf(y0f + 1.f, 0.f), (float)(Hh - 1));
    const float* r00 = pp + (size_t)(y0 * Ww + x0) * 128;
    const float* r01 = pp + (size_t)(y0 * Ww + x1) * 128;
    const float* r10 = pp + (size_t)(y1 * Ww + x0) * 128;
    const float* r11 = pp + (size_t)(y1 * Ww + x1) * 128;
    return wy0 * (wx0 * r00[j] + wx1 * r01[j]) + wy1 * (wx0 * r10[j] + wx1 * r11[j]);
}

__global__ __launch_bounds__(128) void sample_bottleneck_k(
    const float* __restrict__ av, const float* __restrict__ pp1, const float* __restrict__ pp2,
    const float* __restrict__ pp3, const float* __restrict__ pp4, const float* __restrict__ bb,
    const float* __restrict__ verts, const float* __restrict__ encp,
    const float* __restrict__ g0w0, const float* __restrict__ g0w1,
    const float* __restrict__ g0b0, const float* __restrict__ g0b1,
    unsigned short* __restrict__ X, unsigned short* __restrict__ H, int V_, int B_) {
    int n = blockIdx.x, j = threadIdx.x;
    int b = n / V_;
    float gx = av[(size_t)n * 3 + 0];
    float gy = av[(size_t)n * 3 + 1];
    float acc = bb[j];
    acc += sample_level(pp1 + (size_t)b * 3136 * 128, 56, 56, gx, gy, j);
    acc += sample_level(pp2 + (size_t)b * 784 * 128, 28, 28, gx, gy, j);
    acc += sample_level(pp3 + (size_t)b * 196 * 128, 14, 14, gx, gy, j);
    acc += sample_level(pp4 + (size_t)b * 49 * 128, 7, 7, gx, gy, j);
    X[(size_t)n * 128 + j] = f2bf(fmaxf(acc, 0.f));
    float v0 = verts[n * 3 + 0], v1 = verts[n * 3 + 1], v2 = verts[n * 3 + 2];
    float h0 = encp[(0 * B_ + b) * 128 + j] + g0b0[j] + v0 * g0w0[128 * 128 + j] +
               v1 * g0w0[129 * 128 + j] + v2 * g0w0[130 * 128 + j];
    float h1 = encp[(1 * B_ + b) * 128 + j] + g0b1[j] + v0 * g0w1[128 * 128 + j] +
               v1 * g0w1[129 * 128 + j] + v2 * g0w1[130 * 128 + j];
    H[(size_t)n * 256 + j] = f2bf(h0);
    H[(size_t)n * 256 + 128 + j] = f2bf(h1);
}

// ---------------- layer-0 pre: pre[n] = h0pre[n] + sum_nb h1pre[nb] (fp32) ----------------
__global__ __launch_bounds__(256) void aggpre_k(const unsigned short* __restrict__ H,
                                                const int* __restrict__ rowptr,
                                                const int* __restrict__ adj,
                                                float* __restrict__ pre, int Nv) {
    int wave = threadIdx.x >> 6, lane = threadIdx.x & 63;
    int n = blockIdx.x * 4 + wave;
    if (n >= Nv) return;
    unsigned int u = *(const unsigned int*)(H + (size_t)n * 256 + 2 * lane);
    float a0 = bf2f((unsigned short)(u & 0xffff));
    float a1 = bf2f((unsigned short)(u >> 16));
    int s = rowptr[n], e = rowptr[n + 1];
    for (int t = s; t < e; ++t) {
        int nb = adj[t];
        unsigned int w = *(const unsigned int*)(H + (size_t)nb * 256 + 128 + 2 * lane);
        a0 += bf2f((unsigned short)(w & 0xffff));
        a1 += bf2f((unsigned short)(w >> 16));
    }
    pre[(size_t)n * 128 + 2 * lane] = a0;
    pre[(size_t)n * 128 + 2 * lane + 1] = a1;
}

// ---------------- neighbor aggregation: Agg[n] = sum_nb X[nb] (bf16, fp32 acc) ----------------
__global__ __launch_bounds__(256) void agg_x_k(const unsigned short* __restrict__ X,
                                               const int* __restrict__ rowptr,
                                               const int* __restrict__ adj,
                                               unsigned short* __restrict__ Agg, int Nv) {
    int wave = threadIdx.x >> 6, lane = threadIdx.x & 63;
    int n = blockIdx.x * 4 + wave;
    if (n >= Nv) return;
    const unsigned int* Xu = (const unsigned int*)X;
    float a0 = 0.f, a1 = 0.f;
    int s = rowptr[n], e = rowptr[n + 1];
    for (int t = s; t < e; ++t) {
        int nb = adj[t];
        unsigned int w = Xu[(size_t)nb * 64 + lane];
        a0 += bf2f((unsigned short)(w & 0xffff));
        a1 += bf2f((unsigned short)(w >> 16));
    }
    unsigned int o = (unsigned int)f2bf(a0) | ((unsigned int)f2bf(a1) << 16);
    *(unsigned int*)(Agg + (size_t)n * 128 + 2 * lane) = o;
}

// ---------------- dual-MFMA layer GEMM: X' = relu(X@W0 + Agg@W1 + b0 + deg*b1 (+pre)) ----------------
// 128-row tiles, 4 waves x 32 rows. Weights (W0|W1, 64 KB) staged in LDS, XOR-swizzled,
// read via ds_read_b128. X/Agg A-fragments loaded DIRECTLY from global (no cross-block reuse).
// Epilogue reuses the weight LDS region as bf16 staging for coalesced stores / fused head.
__global__ __launch_bounds__(256, 2) void gemm_dual_k(
    const unsigned short* __restrict__ Xin, const unsigned short* __restrict__ Agg,
    const unsigned short* __restrict__ Wt,  // [2][128][128] bf16 n-major (W0, W1)
    const float* __restrict__ b0, const float* __restrict__ b1,
    const float* __restrict__ pre, const int* __restrict__ deg,
    unsigned short* __restrict__ Xout, const float* __restrict__ off_w,
    const float* __restrict__ off_b, float* __restrict__ out, int last, int M) {
    __shared__ unsigned short lds[32768];  // 64 KB weights; reused as Cs in epilogue
    __shared__ float bS[256];
    __shared__ float owS[384];
    __shared__ float phS[768];

    int tid = threadIdx.x;
    int m0 = blockIdx.x * 128;

    if (tid < 128) {
        bS[tid] = b0 ? b0[tid] : 0.f;
        bS[128 + tid] = b1 ? b1[tid] : 0.f;
    }
    if (last) {
        for (int i = tid; i < 384; i += 256) owS[i] = off_w[i];
    }

    // stage W0|W1 coalesced, XOR-swizzled 16B chunks
#pragma unroll
    for (int l = 0; l < 16; ++l) {
        int idx = tid + l * 256;        // 0..4095 chunk slots
        int half = idx >> 11;           // 0..1
        int r = (idx >> 4) & 127;       // weight row (n)
        int c16 = idx & 15;             // 16B chunk along k
        int sw = (c16 ^ (r & 15)) * 8;
        *(short8*)&lds[half * 16384 + r * 128 + sw] =
            *(const short8*)(Wt + half * 16384 + r * 128 + c16 * 8);
    }
    __syncthreads();

    int wave = tid >> 6, lane = tid & 63;
    int row16 = lane & 15;
    int quad = lane >> 4;
    int wrow = wave * 32;

    floatx4 acc[2][8];
#pragma unroll
    for (int i = 0; i < 2; i++)
#pragma unroll
        for (int j = 0; j < 8; j++) acc[i][j] = (floatx4){0.f, 0.f, 0.f, 0.f};

#pragma unroll
    for (int ks = 0; ks < 4; ++ks) {
        int koff = ks * 32 + quad * 8;
        int g0 = min(m0 + wrow + row16, M - 1);
        int g1 = min(m0 + wrow + 16 + row16, M - 1);
        short8 ax0 = *(const short8*)(Xin + (size_t)g0 * 128 + koff);
        short8 ax1 = *(const short8*)(Xin + (size_t)g1 * 128 + koff);
        short8 ag0 = *(const short8*)(Agg + (size_t)g0 * 128 + koff);
        short8 ag1 = *(const short8*)(Agg + (size_t)g1 * 128 + koff);
        int c = ks * 4 + quad;
#pragma unroll
        for (int nt = 0; nt < 8; ++nt) {
            int wr = nt * 16 + row16;
            short8 bw0 = *(short8*)&lds[wr * 128 + ((c ^ row16) * 8)];
            short8 bw1 = *(short8*)&lds[16384 + wr * 128 + ((c ^ row16) * 8)];
            acc[0][nt] = __builtin_amdgcn_mfma_f32_16x16x32_bf16(ax0, bw0, acc[0][nt], 0, 0, 0);
            acc[0][nt] = __builtin_amdgcn_mfma_f32_16x16x32_bf16(ag0, bw1, acc[0][nt], 0, 0, 0);
            acc[1][nt] = __builtin_amdgcn_mfma_f32_16x16x32_bf16(ax1, bw0, acc[1][nt], 0, 0, 0);
            acc[1][nt] = __builtin_amdgcn_mfma_f32_16x16x32_bf16(ag1, bw1, acc[1][nt], 0, 0, 0);
        }
    }
    __syncthreads();  // weights consumed; reuse lds as Cs (128 x pitch-136 = 34816 B)

    unsigned short* Cs = lds;
#pragma unroll
    for (int rt = 0; rt < 2; ++rt) {
#pragma unroll
        for (int nt = 0; nt < 8; ++nt) {
            int col = nt * 16 + row16;
            float bc0 = bS[col];
            float bc1 = bS[128 + col];
#pragma unroll
            for (int rr = 0; rr < 4; ++rr) {
                int row = wrow + rt * 16 + quad * 4 + rr;
                int gm = m0 + row;
                float v = acc[rt][nt][rr] + bc0;
                if (gm < M) {
                    v += (float)deg[gm] * bc1;
                    if (pre) v += pre[(size_t)gm * 128 + col];
                }
                Cs[row * 136 + col] = f2bf(fmaxf(v, 0.f));
            }
        }
    }
    __syncthreads();

    if (!last) {
        int r = tid >> 1;
        int ch = (tid & 1) * 64;
        int gm = m0 + r;
        if (gm < M) {
#pragma unroll
            for (int c = 0; c < 64; c += 8)
                *(short8*)(Xout + (size_t)gm * 128 + ch + c) = *(short8*)&Cs[r * 136 + ch + c];
        }
    } else {
        int r = tid >> 1;
        int cbase = (tid & 1) * 64;
        float p0 = 0.f, p1 = 0.f, p2 = 0.f;
#pragma unroll 16
        for (int c = 0; c < 64; ++c) {
            float x = bf2f(Cs[r * 136 + cbase + c]);
            p0 = fmaf(x, owS[(cbase + c) * 3 + 0], p0);
            p1 = fmaf(x, owS[(cbase + c) * 3 + 1], p1);
            p2 = fmaf(x, owS[(cbase + c) * 3 + 2], p2);
        }
        phS[tid * 3 + 0] = p0;
        phS[tid * 3 + 1] = p1;
        phS[tid * 3 + 2] = p2;
        __syncthreads();
        if (tid < 128) {
            int gm = m0 + tid;
            if (gm < M) {
#pragma unroll
                for (int c = 0; c < 3; ++c) {
                    out[gm * 3 + c] =
                        phS[(tid * 2) * 3 + c] + phS[(tid * 2 + 1) * 3 + c] + off_b[c];
                }
            }
        }
    }
}

extern "C" void kernel_launch(void* const* d_in, const int* in_sizes, int n_in, void* d_out,
                              int out_size, void* d_ws, size_t ws_size, hipStream_t stream) {
    const float* feat1 = (const float*)d_in[0];
    const float* feat2 = (const float*)d_in[1];
    const float* feat3 = (const float*)d_in[2];
    const float* feat4 = (const float*)d_in[3];
    const float* av = (const float*)d_in[4];
    const float* verts = (const float*)d_in[5];
    const float* image_enc = (const float*)d_in[6];
    const int* edges = (const int*)d_in[7];
    const float* bw = (const float*)d_in[8];
    const float* bb = (const float*)d_in[9];
    const float* g0w0 = (const float*)d_in[10];
    const float* g0b0 = (const float*)d_in[11];
    const float* g0w1 = (const float*)d_in[12];
    const float* g0b1 = (const float*)d_in[13];
    const float* gw0 = (const float*)d_in[14];
    const float* gb0 = (const float*)d_in[15];
    const float* gw1 = (const float*)d_in[16];
    const float* gb1 = (const float*)d_in[17];
    const float* off_w = (const float*)d_in[18];
    const float* off_b = (const float*)d_in[19];

    int B_ = in_sizes[6] / 256;  // 4
    int N_ = in_sizes[5] / 3;    // 40968
    int V_ = N_ / B_;            // 10242
    int E_ = in_sizes[7] / 2;    // 122880

    char* wsb = (char*)d_ws;
    size_t off = 0;
    auto alloc = [&](size_t bytes) -> void* {
        void* p = (void*)(wsb + off);
        off += (bytes + 255) & ~(size_t)255;
        return p;
    };
    float* pp1 = (float*)alloc((size_t)B_ * 3136 * 128 * 4);
    float* pp2 = (float*)alloc((size_t)B_ * 784 * 128 * 4);
    float* pp3 = (float*)alloc((size_t)B_ * 196 * 128 * 4);
    float* pp4 = (float*)alloc((size_t)B_ * 49 * 128 * 4);
    unsigned short* XA = (unsigned short*)alloc((size_t)N_ * 128 * 2);
    unsigned short* XB = (unsigned short*)alloc((size_t)N_ * 128 * 2);
    unsigned short* AggB = (unsigned short*)alloc((size_t)N_ * 128 * 2);
    unsigned short* Hb = (unsigned short*)alloc((size_t)N_ * 256 * 2);
    float* pre = (float*)alloc((size_t)N_ * 128 * 4);
    unsigned short* Wt = (unsigned short*)alloc((size_t)8 * 2 * 128 * 128 * 2);
    float* encp = (float*)alloc((size_t)2 * B_ * 128 * 4);
    int* deg = (int*)alloc((size_t)(N_ + 1) * 4);
    int* rowptr = (int*)alloc((size_t)(N_ + 1) * 4);
    int* cursor = (int*)alloc((size_t)N_ * 4);
    int* excl = (int*)alloc((size_t)N_ * 4);
    int* bsum = (int*)alloc((size_t)64 * 4);
    int* adj = (int*)alloc((size_t)2 * E_ * 4);

    // K-split partial buffers alias XA/XB (dead until sample_bottleneck_k)
    int S2 = B_ * 784 * 128;
    int S3 = B_ * 196 * 128;
    int S4 = B_ * 49 * 128;
    float* pp2p = (float*)XA;
    float* pp3p = (float*)XB;
    float* pp4p = (float*)((char*)XB + (size_t)8 * S3 * 4);

    // CSR build
    hipMemsetAsync(deg, 0, (N_ + 1) * sizeof(int), stream);
    count_deg_k<<<ceil_div(E_, 256), 256, 0, stream>>>(edges, deg, E_);
    int nb = ceil_div(N_, 1024);
    scan1_k<<<nb, 1024, 0, stream>>>(deg, excl, bsum, N_);
    scan2_k<<<1, 64, 0, stream>>>(bsum, nb);
    scan3_k<<<nb, 1024, 0, stream>>>(excl, bsum, deg, rowptr, cursor, N_);
    fill_adj_k<<<ceil_div(E_, 256), 256, 0, stream>>>(edges, cursor, adj, E_);

    // weight prep + enc projection
    prep_w_k<<<16, 256, 0, stream>>>(g0w0, g0w1, gw0, gw1, Wt);
    enc_proj_k<<<dim3(B_, 2), 128, 0, stream>>>(image_enc, g0w0, g0w1, encp, B_);

    // pixel projections: feat1 direct; feat2/3/4 K-split to partials + reduce
    gemm_proj_k<<<dim3(49, B_, 1), 256, 0, stream>>>(feat1, bw + 0 * 128, pp1, 256, 3136, 256, 0);
    gemm_proj_k<<<dim3(13, B_, 4), 256, 0, stream>>>(feat2, bw + 256 * 128, pp2p, 512, 784, 128, S2);
    gemm_proj_k<<<dim3(4, B_, 8), 256, 0, stream>>>(feat3, bw + 768 * 128, pp3p, 1024, 196, 128, S3);
    gemm_proj_k<<<dim3(1, B_, 16), 256, 0, stream>>>(feat4, bw + 1792 * 128, pp4p, 2048, 49, 128, S4);
    reduce_pp_k<<<ceil_div((S2 + S3 + S4) / 4, 256), 256, 0, stream>>>(pp2p, pp3p, pp4p, pp2,
                                                                       pp3, pp4, S2, S3, S4);

    // sample + bottleneck -> XA (bf16 X0); layer0 pre terms (biases baked) -> Hb (bf16)
    sample_bottleneck_k<<<N_, 128, 0, stream>>>(av, pp1, pp2, pp3, pp4, bb, verts, encp, g0w0,
                                                g0w1, g0b0, g0b1, XA, Hb, V_, B_);

    // layer0 pre = h0pre + sum_nb h1pre
    aggpre_k<<<ceil_div(N_, 4), 256, 0, stream>>>(Hb, rowptr, adj, pre, N_);

    int agrid = ceil_div(N_, 4);
    int ggrid = ceil_div(N_, 128);
    // layer 0: pre supplies all affine terms
    agg_x_k<<<agrid, 256, 0, stream>>>(XA, rowptr, adj, AggB, N_);
    gemm_dual_k<<<ggrid, 256, 0, stream>>>(XA, AggB, Wt, nullptr, nullptr, pre, deg, XB, off_w,
                                           off_b, (float*)d_out, 0, N_);
    unsigned short* Xc = XB;
    unsigned short* Xn = XA;
    for (int i = 0; i < 7; ++i) {
        int last = (i == 6) ? 1 : 0;
        agg_x_k<<<agrid, 256, 0, stream>>>(Xc, rowptr, adj, AggB, N_);
        gemm_dual_k<<<ggrid, 256, 0, stream>>>(Xc, AggB, Wt + (size_t)(i + 1) * 32768,
                                               gb0 + i * 128, gb1 + i * 128, nullptr, deg, Xn,
                                               off_w, off_b, (float*)d_out, last, N_);
        unsigned short* t = Xc;
        Xc = Xn;
        Xn = t;
    }
}

// Round 9
// 682.857 us; speedup vs baseline: 1.8777x; 1.0301x over previous
//
#include <hip/hip_runtime.h>

static inline int ceil_div(int a, int b) { return (a + b - 1) / b; }

typedef __attribute__((ext_vector_type(8))) short short8;
typedef __attribute__((ext_vector_type(4))) float floatx4;

__device__ __forceinline__ unsigned short f2bf(float f) {
    unsigned int u = __float_as_uint(f);
    unsigned int r = (u + 0x7fffu + ((u >> 16) & 1u)) >> 16;
    return (unsigned short)r;
}
__device__ __forceinline__ float bf2f(unsigned short h) {
    return __uint_as_float(((unsigned int)h) << 16);
}

// ---------------- CSR build ----------------
__global__ __launch_bounds__(256) void count_deg_k(const int* __restrict__ edges,
                                                   int* __restrict__ deg, int E) {
    int e = blockIdx.x * blockDim.x + threadIdx.x;
    if (e < E) {
        atomicAdd(&deg[edges[2 * e]], 1);
        atomicAdd(&deg[edges[2 * e + 1]], 1);
    }
}

__global__ __launch_bounds__(1024) void scan1_k(const int* __restrict__ deg,
                                                int* __restrict__ excl,
                                                int* __restrict__ bsum, int Nv) {
    __shared__ int s[1024];
    int tid = threadIdx.x;
    int i = blockIdx.x * 1024 + tid;
    int v = (i < Nv) ? deg[i] : 0;
    s[tid] = v;
    __syncthreads();
    for (int off = 1; off < 1024; off <<= 1) {
        int t = (tid >= off) ? s[tid - off] : 0;
        __syncthreads();
        if (tid >= off) s[tid] += t;
        __syncthreads();
    }
    if (i < Nv) excl[i] = s[tid] - v;
    if (tid == 1023) bsum[blockIdx.x] = s[1023];
}

__global__ __launch_bounds__(64) void scan2_k(int* __restrict__ bsum, int nb) {
    __shared__ int s[64];
    int tid = threadIdx.x;
    int v = (tid < nb) ? bsum[tid] : 0;
    s[tid] = v;
    __syncthreads();
    for (int off = 1; off < 64; off <<= 1) {
        int t = (tid >= off) ? s[tid - off] : 0;
        __syncthreads();
        if (tid >= off) s[tid] += t;
        __syncthreads();
    }
    if (tid < nb) bsum[tid] = s[tid] - v;
}

__global__ __launch_bounds__(1024) void scan3_k(const int* __restrict__ excl,
                                                const int* __restrict__ bsum,
                                                const int* __restrict__ deg,
                                                int* __restrict__ rowptr,
                                                int* __restrict__ cursor, int Nv) {
    int i = blockIdx.x * 1024 + threadIdx.x;
    if (i < Nv) {
        int val = excl[i] + bsum[blockIdx.x];
        rowptr[i] = val;
        cursor[i] = val;
        if (i == Nv - 1) rowptr[Nv] = val + deg[i];
    }
}

__global__ __launch_bounds__(256) void fill_adj_k(const int* __restrict__ edges,
                                                  int* __restrict__ cursor,
                                                  int* __restrict__ adj, int E) {
    int e = blockIdx.x * blockDim.x + threadIdx.x;
    if (e < E) {
        int a = edges[2 * e], b = edges[2 * e + 1];
        adj[atomicAdd(&cursor[a], 1)] = b;
        adj[atomicAdd(&cursor[b], 1)] = a;
    }
}

// ---------------- weight prep: fp32 [K][128] -> bf16 transposed [128 n][128 k] ----------------
__global__ __launch_bounds__(256) void prep_w_k(const float* __restrict__ g0w0,
                                                const float* __restrict__ g0w1,
                                                const float* __restrict__ gw0,
                                                const float* __restrict__ gw1,
                                                unsigned short* __restrict__ Wt) {
    int lh = blockIdx.x;
    int l = lh >> 1, h = lh & 1;
    const float* src;
    if (l == 0) src = h ? g0w1 : g0w0;
    else src = (h ? gw1 : gw0) + (size_t)(l - 1) * 16384;
    unsigned short* dst = Wt + (size_t)lh * 16384;
    for (int idx = threadIdx.x; idx < 16384; idx += 256) {
        int n = idx >> 7, k = idx & 127;
        dst[n * 128 + k] = f2bf(src[k * 128 + n]);
    }
}

// ---------------- enc @ g0_w*[131:387] ----------------
__global__ __launch_bounds__(128) void enc_proj_k(const float* __restrict__ enc,
                                                  const float* __restrict__ w0,
                                                  const float* __restrict__ w1,
                                                  float* __restrict__ out, int B_) {
    int b = blockIdx.x, sH = blockIdx.y, j = threadIdx.x;
    const float* w = sH ? w1 : w0;
    const float* eb = enc + b * 256;
    float acc = 0.f;
    for (int c = 0; c < 256; ++c) acc = fmaf(eb[c], w[(131 + c) * 128 + j], acc);
    out[(sH * B_ + b) * 128 + j] = acc;
}

// ---------------- pixel projection, K-split -> disjoint partial buffers ----------------
__global__ __launch_bounds__(256) void gemm_proj_k(const float* __restrict__ fm,
                                                   const float* __restrict__ W,
                                                   float* __restrict__ out, int C, int HW,
                                                   int Cchunk, int S) {
    __shared__ float Xs[32][64];
    __shared__ float Ws[32][128];
    int tid = threadIdx.x;
    int p0 = blockIdx.x * 64;
    int b = blockIdx.y;
    int c0 = blockIdx.z * Cchunk;
    const float* fmb = fm + (size_t)b * C * HW;
    float acc[8][4];
#pragma unroll
    for (int i = 0; i < 8; i++)
#pragma unroll
        for (int j = 0; j < 4; j++) acc[i][j] = 0.f;

    bool vec_ok = ((HW & 3) == 0);
    for (int kc = c0; kc < c0 + Cchunk; kc += 32) {
        {
            int p4 = (tid & 15) * 4;
            int k0 = tid >> 4;
#pragma unroll
            for (int kk = 0; kk < 32; kk += 16) {
                int k = k0 + kk;
                const float* src = fmb + (size_t)(kc + k) * HW + p0 + p4;
                float4 v;
                if (vec_ok && (p0 + p4 + 3 < HW)) {
                    v = *(const float4*)src;
                } else {
                    v.x = (p0 + p4 + 0 < HW) ? src[0] : 0.f;
                    v.y = (p0 + p4 + 1 < HW) ? src[1] : 0.f;
                    v.z = (p0 + p4 + 2 < HW) ? src[2] : 0.f;
                    v.w = (p0 + p4 + 3 < HW) ? src[3] : 0.f;
                }
                *(float4*)&Xs[k][p4] = v;
            }
        }
        {
            int j4 = (tid & 31) * 4;
            int k0 = tid >> 5;
#pragma unroll
            for (int kk = 0; kk < 32; kk += 8) {
                int k = k0 + kk;
                *(float4*)&Ws[k][j4] = *(const float4*)(W + (size_t)(kc + k) * 128 + j4);
            }
        }
        __syncthreads();
        int rb = (tid >> 5) * 8;
        int cb = (tid & 31) * 4;
#pragma unroll 8
        for (int k = 0; k < 32; ++k) {
            float xr[8], wc[4];
#pragma unroll
            for (int i = 0; i < 8; i++) xr[i] = Xs[k][rb + i];
#pragma unroll
            for (int j = 0; j < 4; j++) wc[j] = Ws[k][cb + j];
#pragma unroll
            for (int i = 0; i < 8; i++)
#pragma unroll
                for (int j = 0; j < 4; j++) acc[i][j] = fmaf(xr[i], wc[j], acc[i][j]);
        }
        __syncthreads();
    }
    int rb = (tid >> 5) * 8;
    int cb = (tid & 31) * 4;
    float* obase = out + (size_t)blockIdx.z * S;
#pragma unroll
    for (int i = 0; i < 8; i++) {
        int p = p0 + rb + i;
        if (p < HW) {
            *(float4*)(obase + ((size_t)b * HW + p) * 128 + cb) =
                make_float4(acc[i][0], acc[i][1], acc[i][2], acc[i][3]);
        }
    }
}

// ---------------- reduce partials for levels 2/3/4 ----------------
__global__ __launch_bounds__(256) void reduce_pp_k(const float* __restrict__ p2,
                                                   const float* __restrict__ p3,
                                                   const float* __restrict__ p4,
                                                   float* __restrict__ o2,
                                                   float* __restrict__ o3,
                                                   float* __restrict__ o4, int S2, int S3,
                                                   int S4) {
    int idx4 = blockIdx.x * 256 + threadIdx.x;
    int i = idx4 * 4;
    const float* src;
    float* dst;
    int S, z, base;
    if (i < S2) {
        src = p2; dst = o2; S = S2; z = 4; base = i;
    } else if (i < S2 + S3) {
        src = p3; dst = o3; S = S3; z = 8; base = i - S2;
    } else if (i < S2 + S3 + S4) {
        src = p4; dst = o4; S = S4; z = 16; base = i - S2 - S3;
    } else {
        return;
    }
    float4 a = *(const float4*)(src + base);
    for (int zz = 1; zz < z; ++zz) {
        float4 b = *(const float4*)(src + (size_t)zz * S + base);
        a.x += b.x; a.y += b.y; a.z += b.z; a.w += b.w;
    }
    *(float4*)(dst + base) = a;
}

// ---------------- bilinear sample + bottleneck relu + layer0 pre terms (biases baked in) ----------------
__device__ __forceinline__ float sample_level(const float* __restrict__ pp, int Hh, int Ww,
                                              float gx, float gy, int j) {
    float x = (gx + 1.f) * 0.5f * (float)(Ww - 1);
    float y = (gy + 1.f) * 0.5f * (float)(Hh - 1);
    float x0f = floorf(x), y0f = floorf(y);
    float wx1 = x - x0f, wy1 = y - y0f;
    float wx0 = 1.f - wx1, wy0 = 1.f - wy1;
    int x0 = (int)fminf(fmaxf(x0f, 0.f), (float)(Ww - 1));
    int x1 = (int)fminf(fmaxf(x0f + 1.f, 0.f), (float)(Ww - 1));
    int y0 = (int)fminf(fmaxf(y0f, 0.f), (float)(Hh - 1));
    int y1 = (int)fminf(fmaxf(y0f + 1.f, 0.f), (float)(Hh - 1));
    const float* r00 = pp + (size_t)(y0 * Ww + x0) * 128;
    const float* r01 = pp + (size_t)(y0 * Ww + x1) * 128;
    const float* r10 = pp + (size_t)(y1 * Ww + x0) * 128;
    const float* r11 = pp + (size_t)(y1 * Ww + x1) * 128;
    return wy0 * (wx0 * r00[j] + wx1 * r01[j]) + wy1 * (wx0 * r10[j] + wx1 * r11[j]);
}

__global__ __launch_bounds__(128) void sample_bottleneck_k(
    const float* __restrict__ av, const float* __restrict__ pp1, const float* __restrict__ pp2,
    const float* __restrict__ pp3, const float* __restrict__ pp4, const float* __restrict__ bb,
    const float* __restrict__ verts, const float* __restrict__ encp,
    const float* __restrict__ g0w0, const float* __restrict__ g0w1,
    const float* __restrict__ g0b0, const float* __restrict__ g0b1,
    unsigned short* __restrict__ X, unsigned short* __restrict__ H, int V_, int B_) {
    int n = blockIdx.x, j = threadIdx.x;
    int b = n / V_;
    float gx = av[(size_t)n * 3 + 0];
    float gy = av[(size_t)n * 3 + 1];
    float acc = bb[j];
    acc += sample_level(pp1 + (size_t)b * 3136 * 128, 56, 56, gx, gy, j);
    acc += sample_level(pp2 + (size_t)b * 784 * 128, 28, 28, gx, gy, j);
    acc += sample_level(pp3 + (size_t)b * 196 * 128, 14, 14, gx, gy, j);
    acc += sample_level(pp4 + (size_t)b * 49 * 128, 7, 7, gx, gy, j);
    X[(size_t)n * 128 + j] = f2bf(fmaxf(acc, 0.f));
    float v0 = verts[n * 3 + 0], v1 = verts[n * 3 + 1], v2 = verts[n * 3 + 2];
    float h0 = encp[(0 * B_ + b) * 128 + j] + g0b0[j] + v0 * g0w0[128 * 128 + j] +
               v1 * g0w0[129 * 128 + j] + v2 * g0w0[130 * 128 + j];
    float h1 = encp[(1 * B_ + b) * 128 + j] + g0b1[j] + v0 * g0w1[128 * 128 + j] +
               v1 * g0w1[129 * 128 + j] + v2 * g0w1[130 * 128 + j];
    H[(size_t)n * 256 + j] = f2bf(h0);
    H[(size_t)n * 256 + 128 + j] = f2bf(h1);
}

// ---------------- layer-0 pre: pre[n] = h0pre[n] + sum_nb h1pre[nb] (fp32) ----------------
__global__ __launch_bounds__(256) void aggpre_k(const unsigned short* __restrict__ H,
                                                const int* __restrict__ rowptr,
                                                const int* __restrict__ adj,
                                                float* __restrict__ pre, int Nv) {
    int wave = threadIdx.x >> 6, lane = threadIdx.x & 63;
    int n = blockIdx.x * 4 + wave;
    if (n >= Nv) return;
    unsigned int u = *(const unsigned int*)(H + (size_t)n * 256 + 2 * lane);
    float a0 = bf2f((unsigned short)(u & 0xffff));
    float a1 = bf2f((unsigned short)(u >> 16));
    int s = rowptr[n], e = rowptr[n + 1];
    for (int t = s; t < e; ++t) {
        int nb = adj[t];
        unsigned int w = *(const unsigned int*)(H + (size_t)nb * 256 + 128 + 2 * lane);
        a0 += bf2f((unsigned short)(w & 0xffff));
        a1 += bf2f((unsigned short)(w >> 16));
    }
    pre[(size_t)n * 128 + 2 * lane] = a0;
    pre[(size_t)n * 128 + 2 * lane + 1] = a1;
}

// ---------------- neighbor aggregation: Agg[n] = sum_nb X[nb] (bf16, fp32 acc) ----------------
__global__ __launch_bounds__(256) void agg_x_k(const unsigned short* __restrict__ X,
                                               const int* __restrict__ rowptr,
                                               const int* __restrict__ adj,
                                               unsigned short* __restrict__ Agg, int Nv) {
    int wave = threadIdx.x >> 6, lane = threadIdx.x & 63;
    int n = blockIdx.x * 4 + wave;
    if (n >= Nv) return;
    const unsigned int* Xu = (const unsigned int*)X;
    float a0 = 0.f, a1 = 0.f;
    int s = rowptr[n], e = rowptr[n + 1];
    for (int t = s; t < e; ++t) {
        int nb = adj[t];
        unsigned int w = Xu[(size_t)nb * 64 + lane];
        a0 += bf2f((unsigned short)(w & 0xffff));
        a1 += bf2f((unsigned short)(w >> 16));
    }
    unsigned int o = (unsigned int)f2bf(a0) | ((unsigned int)f2bf(a1) << 16);
    *(unsigned int*)(Agg + (size_t)n * 128 + 2 * lane) = o;
}

// ---------------- dual-MFMA layer GEMM, 64x64 tiles for TLP ----------------
// X' = relu(X@W0 + Agg@W1 + b0 + deg*b1 (+pre)). grid = (ceil(M/64), 2).
// blockIdx.y selects output cols [yb*64, yb*64+64). Weight halves (32 KB) in LDS,
// XOR-swizzled; A-fragments direct from global. 4 blocks/CU target.
__global__ __launch_bounds__(256, 4) void gemm_dual_k(
    const unsigned short* __restrict__ Xin, const unsigned short* __restrict__ Agg,
    const unsigned short* __restrict__ Wt,  // [2][128][128] bf16 n-major (W0, W1)
    const float* __restrict__ b0, const float* __restrict__ b1,
    const float* __restrict__ pre, const int* __restrict__ deg,
    unsigned short* __restrict__ Xout, int M) {
    __shared__ unsigned short lds[16384];  // 32 KB: W0half [0,8192), W1half [8192,16384)
    __shared__ float bS[128];

    int tid = threadIdx.x;
    int m0 = blockIdx.x * 64;
    int yb = blockIdx.y;

    if (tid < 64) {
        bS[tid] = b0 ? b0[yb * 64 + tid] : 0.f;
        bS[64 + tid] = b1 ? b1[yb * 64 + tid] : 0.f;
    }

    const unsigned short* W0h = Wt + (size_t)yb * 64 * 128;
    const unsigned short* W1h = Wt + 16384 + (size_t)yb * 64 * 128;
    // stage both weight halves: 2048 16B-chunks, 8 per thread
#pragma unroll
    for (int l = 0; l < 8; ++l) {
        int idx = tid + l * 256;      // 0..2047
        int half = idx >> 10;         // 0..1
        int r = (idx >> 4) & 63;      // weight row within half
        int c16 = idx & 15;
        int sw = (c16 ^ (r & 15)) * 8;
        const unsigned short* src = (half ? W1h : W0h) + r * 128 + c16 * 8;
        *(short8*)&lds[half * 8192 + r * 128 + sw] = *(const short8*)src;
    }
    __syncthreads();

    int wave = tid >> 6, lane = tid & 63;
    int row16 = lane & 15;
    int quad = lane >> 4;
    int wrow = wave * 16;

    floatx4 acc[4];
#pragma unroll
    for (int j = 0; j < 4; j++) acc[j] = (floatx4){0.f, 0.f, 0.f, 0.f};

#pragma unroll
    for (int ks = 0; ks < 4; ++ks) {
        int koff = ks * 32 + quad * 8;
        int g = min(m0 + wrow + row16, M - 1);
        short8 ax = *(const short8*)(Xin + (size_t)g * 128 + koff);
        short8 ag = *(const short8*)(Agg + (size_t)g * 128 + koff);
        int c = ks * 4 + quad;
#pragma unroll
        for (int nt = 0; nt < 4; ++nt) {
            int wr = nt * 16 + row16;
            short8 bw0 = *(short8*)&lds[wr * 128 + ((c ^ row16) * 8)];
            short8 bw1 = *(short8*)&lds[8192 + wr * 128 + ((c ^ row16) * 8)];
            acc[nt] = __builtin_amdgcn_mfma_f32_16x16x32_bf16(ax, bw0, acc[nt], 0, 0, 0);
            acc[nt] = __builtin_amdgcn_mfma_f32_16x16x32_bf16(ag, bw1, acc[nt], 0, 0, 0);
        }
    }
    __syncthreads();  // weights consumed; reuse lds as Cs (64 x pitch-72 bf16 = 9216 B)

    unsigned short* Cs = lds;
#pragma unroll
    for (int nt = 0; nt < 4; ++nt) {
        int colh = nt * 16 + row16;
        int colg = yb * 64 + colh;
        float bc0 = bS[colh];
        float bc1 = bS[64 + colh];
#pragma unroll
        for (int rr = 0; rr < 4; ++rr) {
            int row = wrow + quad * 4 + rr;
            int gm = m0 + row;
            float v = acc[nt][rr] + bc0;
            if (gm < M) {
                v += (float)deg[gm] * bc1;
                if (pre) v += pre[(size_t)gm * 128 + colg];
            }
            Cs[row * 72 + colh] = f2bf(fmaxf(v, 0.f));
        }
    }
    __syncthreads();

    int r = tid >> 2;
    int cq = (tid & 3) * 16;
    int gm = m0 + r;
    if (gm < M) {
        unsigned short* dst = Xout + (size_t)gm * 128 + yb * 64 + cq;
        *(short8*)dst = *(short8*)&Cs[r * 72 + cq];
        *(short8*)(dst + 8) = *(short8*)&Cs[r * 72 + cq + 8];
    }
}

// ---------------- head: out = X @ off_w + off_b (wave per vertex) ----------------
__global__ __launch_bounds__(256) void head_k(const unsigned short* __restrict__ X,
                                              const float* __restrict__ off_w,
                                              const float* __restrict__ off_b,
                                              float* __restrict__ out, int Nv) {
    int wave = threadIdx.x >> 6, lane = threadIdx.x & 63;
    int n = blockIdx.x * 4 + wave;
    if (n >= Nv) return;
    unsigned int u = *(const unsigned int*)(X + (size_t)n * 128 + 2 * lane);
    float x0 = bf2f((unsigned short)(u & 0xffff));
    float x1 = bf2f((unsigned short)(u >> 16));
    int c0 = 2 * lane, c1 = 2 * lane + 1;
    float p0 = x0 * off_w[c0 * 3 + 0] + x1 * off_w[c1 * 3 + 0];
    float p1 = x0 * off_w[c0 * 3 + 1] + x1 * off_w[c1 * 3 + 1];
    float p2 = x0 * off_w[c0 * 3 + 2] + x1 * off_w[c1 * 3 + 2];
#pragma unroll
    for (int m = 1; m < 64; m <<= 1) {
        p0 += __shfl_xor(p0, m);
        p1 += __shfl_xor(p1, m);
        p2 += __shfl_xor(p2, m);
    }
    if (lane == 0) {
        out[n * 3 + 0] = p0 + off_b[0];
        out[n * 3 + 1] = p1 + off_b[1];
        out[n * 3 + 2] = p2 + off_b[2];
    }
}

extern "C" void kernel_launch(void* const* d_in, const int* in_sizes, int n_in, void* d_out,
                              int out_size, void* d_ws, size_t ws_size, hipStream_t stream) {
    const float* feat1 = (const float*)d_in[0];
    const float* feat2 = (const float*)d_in[1];
    const float* feat3 = (const float*)d_in[2];
    const float* feat4 = (const float*)d_in[3];
    const float* av = (const float*)d_in[4];
    const float* verts = (const float*)d_in[5];
    const float* image_enc = (const float*)d_in[6];
    const int* edges = (const int*)d_in[7];
    const float* bw = (const float*)d_in[8];
    const float* bb = (const float*)d_in[9];
    const float* g0w0 = (const float*)d_in[10];
    const float* g0b0 = (const float*)d_in[11];
    const float* g0w1 = (const float*)d_in[12];
    const float* g0b1 = (const float*)d_in[13];
    const float* gw0 = (const float*)d_in[14];
    const float* gb0 = (const float*)d_in[15];
    const float* gw1 = (const float*)d_in[16];
    const float* gb1 = (const float*)d_in[17];
    const float* off_w = (const float*)d_in[18];
    const float* off_b = (const float*)d_in[19];

    int B_ = in_sizes[6] / 256;  // 4
    int N_ = in_sizes[5] / 3;    // 40968
    int V_ = N_ / B_;            // 10242
    int E_ = in_sizes[7] / 2;    // 122880

    char* wsb = (char*)d_ws;
    size_t off = 0;
    auto alloc = [&](size_t bytes) -> void* {
        void* p = (void*)(wsb + off);
        off += (bytes + 255) & ~(size_t)255;
        return p;
    };
    float* pp1 = (float*)alloc((size_t)B_ * 3136 * 128 * 4);
    float* pp2 = (float*)alloc((size_t)B_ * 784 * 128 * 4);
    float* pp3 = (float*)alloc((size_t)B_ * 196 * 128 * 4);
    float* pp4 = (float*)alloc((size_t)B_ * 49 * 128 * 4);
    unsigned short* XA = (unsigned short*)alloc((size_t)N_ * 128 * 2);
    unsigned short* XB = (unsigned short*)alloc((size_t)N_ * 128 * 2);
    unsigned short* AggB = (unsigned short*)alloc((size_t)N_ * 128 * 2);
    unsigned short* Hb = (unsigned short*)alloc((size_t)N_ * 256 * 2);
    float* pre = (float*)alloc((size_t)N_ * 128 * 4);
    unsigned short* Wt = (unsigned short*)alloc((size_t)8 * 2 * 128 * 128 * 2);
    float* encp = (float*)alloc((size_t)2 * B_ * 128 * 4);
    int* deg = (int*)alloc((size_t)(N_ + 1) * 4);
    int* rowptr = (int*)alloc((size_t)(N_ + 1) * 4);
    int* cursor = (int*)alloc((size_t)N_ * 4);
    int* excl = (int*)alloc((size_t)N_ * 4);
    int* bsum = (int*)alloc((size_t)64 * 4);
    int* adj = (int*)alloc((size_t)2 * E_ * 4);

    // K-split partial buffers alias XA/XB (dead until sample_bottleneck_k)
    int S2 = B_ * 784 * 128;
    int S3 = B_ * 196 * 128;
    int S4 = B_ * 49 * 128;
    float* pp2p = (float*)XA;
    float* pp3p = (float*)XB;
    float* pp4p = (float*)((char*)XB + (size_t)8 * S3 * 4);

    // CSR build
    hipMemsetAsync(deg, 0, (N_ + 1) * sizeof(int), stream);
    count_deg_k<<<ceil_div(E_, 256), 256, 0, stream>>>(edges, deg, E_);
    int nb = ceil_div(N_, 1024);
    scan1_k<<<nb, 1024, 0, stream>>>(deg, excl, bsum, N_);
    scan2_k<<<1, 64, 0, stream>>>(bsum, nb);
    scan3_k<<<nb, 1024, 0, stream>>>(excl, bsum, deg, rowptr, cursor, N_);
    fill_adj_k<<<ceil_div(E_, 256), 256, 0, stream>>>(edges, cursor, adj, E_);

    // weight prep + enc projection
    prep_w_k<<<16, 256, 0, stream>>>(g0w0, g0w1, gw0, gw1, Wt);
    enc_proj_k<<<dim3(B_, 2), 128, 0, stream>>>(image_enc, g0w0, g0w1, encp, B_);

    // pixel projections: feat1 direct; feat2/3/4 K-split to partials + reduce
    gemm_proj_k<<<dim3(49, B_, 1), 256, 0, stream>>>(feat1, bw + 0 * 128, pp1, 256, 3136, 256, 0);
    gemm_proj_k<<<dim3(13, B_, 4), 256, 0, stream>>>(feat2, bw + 256 * 128, pp2p, 512, 784, 128, S2);
    gemm_proj_k<<<dim3(4, B_, 8), 256, 0, stream>>>(feat3, bw + 768 * 128, pp3p, 1024, 196, 128, S3);
    gemm_proj_k<<<dim3(1, B_, 16), 256, 0, stream>>>(feat4, bw + 1792 * 128, pp4p, 2048, 49, 128, S4);
    reduce_pp_k<<<ceil_div((S2 + S3 + S4) / 4, 256), 256, 0, stream>>>(pp2p, pp3p, pp4p, pp2,
                                                                       pp3, pp4, S2, S3, S4);

    // sample + bottleneck -> XA (bf16 X0); layer0 pre terms (biases baked) -> Hb (bf16)
    sample_bottleneck_k<<<N_, 128, 0, stream>>>(av, pp1, pp2, pp3, pp4, bb, verts, encp, g0w0,
                                                g0w1, g0b0, g0b1, XA, Hb, V_, B_);

    // layer0 pre = h0pre + sum_nb h1pre
    aggpre_k<<<ceil_div(N_, 4), 256, 0, stream>>>(Hb, rowptr, adj, pre, N_);

    int agrid = ceil_div(N_, 4);
    dim3 ggrid(ceil_div(N_, 64), 2);
    // layer 0: pre supplies all affine terms
    agg_x_k<<<agrid, 256, 0, stream>>>(XA, rowptr, adj, AggB, N_);
    gemm_dual_k<<<ggrid, 256, 0, stream>>>(XA, AggB, Wt, nullptr, nullptr, pre, deg, XB, N_);
    unsigned short* Xc = XB;
    unsigned short* Xn = XA;
    for (int i = 0; i < 7; ++i) {
        agg_x_k<<<agrid, 256, 0, stream>>>(Xc, rowptr, adj, AggB, N_);
        gemm_dual_k<<<ggrid, 256, 0, stream>>>(Xc, AggB, Wt + (size_t)(i + 1) * 32768,
                                               gb0 + i * 128, gb1 + i * 128, nullptr, deg, Xn,
                                               N_);
        unsigned short* t = Xc;
        Xc = Xn;
        Xn = t;
    }
    head_k<<<ceil_div(N_, 4), 256, 0, stream>>>(Xc, off_w, off_b, (float*)d_out, N_);
}